// Round 1
// baseline (1132.194 us; speedup 1.0000x reference)
//
#include <hip/hip_runtime.h>
#include <cstdint>
#include <cstddef>

#define N_NODES 10000
#define N_EDGES 320000
#define FIN 256
#define FOUT 512
#define BN_EPS 1e-5f

// ---------------- BN column stats: sums[c]=sum, sums[F+c]=sumsq ----------------
__global__ void col_stats(const float* __restrict__ X, int nrows, int F,
                          int rows_per_blk, float* __restrict__ sums) {
  int c = threadIdx.x;  // blockDim.x == F
  int r0 = blockIdx.x * rows_per_blk;
  int r1 = min(r0 + rows_per_blk, nrows);
  float s = 0.f, q = 0.f;
  for (int r = r0; r < r1; ++r) {
    float v = X[(size_t)r * F + c];
    s += v;
    q = fmaf(v, v, q);
  }
  atomicAdd(&sums[c], s);
  atomicAdd(&sums[F + c], q);
}

// ---------------- finalize: ab[c] = scale, ab[F+c] = shift ----------------
__global__ void finalize_stats(const float* __restrict__ sums,
                               const float* __restrict__ gamma,
                               const float* __restrict__ beta,
                               float* __restrict__ ab, int F, float invN) {
  int c = blockIdx.x * blockDim.x + threadIdx.x;
  if (c < F) {
    float mu = sums[c] * invN;
    float var = fmaf(-mu, mu, sums[F + c] * invN);  // E[x^2]-mu^2 (biased)
    float s = rsqrtf(var + BN_EPS) * gamma[c];
    ab[c] = s;
    ab[F + c] = fmaf(-mu, s, beta[c]);
  }
}

// ---------------- apply BN + ReLU (elementwise) ----------------
__global__ void bn_relu(const float* __restrict__ X, float* __restrict__ H,
                        long total, int mask, const float* __restrict__ ab, int F) {
  long i = (long)blockIdx.x * blockDim.x + threadIdx.x;
  long stride = (long)gridDim.x * blockDim.x;
  for (; i < total; i += stride) {
    int c = (int)(i & mask);
    float v = fmaf(X[i], ab[c], ab[F + c]);
    H[i] = v > 0.f ? v : 0.f;
  }
}

// ---------------- edge degree count ----------------
__global__ void edge_count(const int* __restrict__ dst, int E, float* __restrict__ cnt) {
  int i = blockIdx.x * blockDim.x + threadIdx.x;
  if (i < E) atomicAdd(&cnt[dst[i]], 1.0f);
}

__global__ void invert_cnt(float* __restrict__ cnt, int n) {
  int i = blockIdx.x * blockDim.x + threadIdx.x;
  if (i < n) cnt[i] = 1.0f / fmaxf(cnt[i], 1.0f);
}

// ---------------- scatter add: agg[dst] += H[src] ----------------
__global__ void scatter_add(const float* __restrict__ H, const int* __restrict__ src,
                            const int* __restrict__ dst, int E, int F,
                            float* __restrict__ agg) {
  for (int e = blockIdx.x; e < E; e += gridDim.x) {
    int s = src[e], d = dst[e];
    const float* hs = H + (size_t)s * F;
    float* ad = agg + (size_t)d * F;
    for (int c = threadIdx.x; c < F; c += blockDim.x)
      atomicAdd(&ad[c], hs[c]);
  }
}

// ---------------- mean: agg[i] *= inv_cnt[row] ----------------
__global__ void mean_scale(float* __restrict__ agg, const float* __restrict__ icnt,
                           long total, int shift) {
  long i = (long)blockIdx.x * blockDim.x + threadIdx.x;
  long stride = (long)gridDim.x * blockDim.x;
  for (; i < total; i += stride) agg[i] *= icnt[i >> shift];
}

// ---------------- tiled fp32 GEMM: C = A1@W1 (+ A2@W2) + bias (+ C) ----------------
// A row-major [M,K], W row-major [K,Nc], C [M,Nc]. 64x64 tile, BK=16, 4x4/thread.
template <bool DUAL, bool ACC>
__global__ __launch_bounds__(256)
void gemm64x64(const float* __restrict__ A1, const float* __restrict__ W1,
               const float* __restrict__ A2, const float* __restrict__ W2,
               const float* __restrict__ bias, float* __restrict__ C,
               int M, int K, int Nc) {
  const int BK = 16;
  __shared__ float As1[BK][68];
  __shared__ float Ws1[BK][64];
  __shared__ float As2[DUAL ? BK : 1][68];
  __shared__ float Ws2[DUAL ? BK : 1][64];

  int tid = threadIdx.x;
  int tx = tid & 15, ty = tid >> 4;
  int m0 = blockIdx.y * 64;
  int n0 = blockIdx.x * 64;

  int la_m = tid >> 2;         // 0..63
  int la_k = (tid & 3) * 4;    // 0,4,8,12
  int lw_k = tid >> 4;         // 0..15
  int lw_n = (tid & 15) * 4;   // 0..60

  float acc[4][4] = {};

  for (int k0 = 0; k0 < K; k0 += BK) {
    int gr = m0 + la_m;
    float4 a4 = make_float4(0.f, 0.f, 0.f, 0.f);
    if (gr < M) a4 = *(const float4*)&A1[(size_t)gr * K + k0 + la_k];
    As1[la_k + 0][la_m] = a4.x;
    As1[la_k + 1][la_m] = a4.y;
    As1[la_k + 2][la_m] = a4.z;
    As1[la_k + 3][la_m] = a4.w;
    if constexpr (DUAL) {
      float4 c4 = make_float4(0.f, 0.f, 0.f, 0.f);
      if (gr < M) c4 = *(const float4*)&A2[(size_t)gr * K + k0 + la_k];
      As2[la_k + 0][la_m] = c4.x;
      As2[la_k + 1][la_m] = c4.y;
      As2[la_k + 2][la_m] = c4.z;
      As2[la_k + 3][la_m] = c4.w;
    }
    *(float4*)&Ws1[lw_k][lw_n] = *(const float4*)&W1[(size_t)(k0 + lw_k) * Nc + n0 + lw_n];
    if constexpr (DUAL) {
      *(float4*)&Ws2[lw_k][lw_n] = *(const float4*)&W2[(size_t)(k0 + lw_k) * Nc + n0 + lw_n];
    }
    __syncthreads();

#pragma unroll
    for (int kk = 0; kk < BK; ++kk) {
      float4 a1 = *(const float4*)&As1[kk][ty * 4];
      float4 b1 = *(const float4*)&Ws1[kk][tx * 4];
      float av[4] = {a1.x, a1.y, a1.z, a1.w};
      float bv[4] = {b1.x, b1.y, b1.z, b1.w};
#pragma unroll
      for (int i = 0; i < 4; ++i)
#pragma unroll
        for (int j = 0; j < 4; ++j) acc[i][j] = fmaf(av[i], bv[j], acc[i][j]);
      if constexpr (DUAL) {
        float4 a2 = *(const float4*)&As2[kk][ty * 4];
        float4 b2 = *(const float4*)&Ws2[kk][tx * 4];
        float av2[4] = {a2.x, a2.y, a2.z, a2.w};
        float bv2[4] = {b2.x, b2.y, b2.z, b2.w};
#pragma unroll
        for (int i = 0; i < 4; ++i)
#pragma unroll
          for (int j = 0; j < 4; ++j) acc[i][j] = fmaf(av2[i], bv2[j], acc[i][j]);
      }
    }
    __syncthreads();
  }

  float4 bv = *(const float4*)&bias[n0 + tx * 4];
#pragma unroll
  for (int i = 0; i < 4; ++i) {
    int r = m0 + ty * 4 + i;
    if (r < M) {
      float* cp = &C[(size_t)r * Nc + n0 + tx * 4];
      float4 o;
      o.x = acc[i][0] + bv.x;
      o.y = acc[i][1] + bv.y;
      o.z = acc[i][2] + bv.z;
      o.w = acc[i][3] + bv.w;
      if constexpr (ACC) {
        float4 old = *(const float4*)cp;
        o.x += old.x; o.y += old.y; o.z += old.z; o.w += old.w;
      }
      *(float4*)cp = o;
    }
  }
}

extern "C" void kernel_launch(void* const* d_in, const int* in_sizes, int n_in,
                              void* d_out, int out_size, void* d_ws, size_t ws_size,
                              hipStream_t stream) {
  const float* x = (const float*)d_in[0];
  const int* ei = (const int*)d_in[1];
  const int* src = ei;
  const int* dst = ei + N_EDGES;
  const float* gamma0 = (const float*)d_in[2];
  const float* beta0  = (const float*)d_in[3];
  const float* W0l    = (const float*)d_in[4];
  const float* W0r    = (const float*)d_in[5];
  const float* bias0  = (const float*)d_in[6];
  const float* gamma1 = (const float*)d_in[7];
  const float* beta1  = (const float*)d_in[8];
  const float* W1l    = (const float*)d_in[9];
  const float* W1r    = (const float*)d_in[10];
  const float* bias1  = (const float*)d_in[11];
  const float* Wsc    = (const float*)d_in[12];
  const float* bsc    = (const float*)d_in[13];
  float* out = (float*)d_out;

  float* p = (float*)d_ws;
  float* h0   = p; p += (size_t)N_NODES * FIN;   // BN0+ReLU output
  float* agg0 = p; p += (size_t)N_NODES * FIN;   // layer0 mean-agg
  float* h1   = p; p += (size_t)N_NODES * FOUT;  // SAGE0 out -> BN1+ReLU in place
  float* agg1 = p; p += (size_t)N_NODES * FOUT;  // layer1 mean-agg
  float* cnt  = p; p += N_NODES;                 // in-degree -> 1/max(deg,1)
  float* sums = p; p += 2 * FOUT;                // col sums / sumsq
  float* ab   = p; p += 2 * FOUT;                // BN scale / shift

  // zero the accumulators (cnt..ab are contiguous)
  hipMemsetAsync(agg0, 0, (size_t)N_NODES * FIN * 4, stream);
  hipMemsetAsync(agg1, 0, (size_t)N_NODES * FOUT * 4, stream);
  hipMemsetAsync(cnt, 0, (size_t)(N_NODES + 4 * FOUT) * 4, stream);

  // ---- degree (shared by both layers) ----
  edge_count<<<(N_EDGES + 255) / 256, 256, 0, stream>>>(dst, N_EDGES, cnt);
  invert_cnt<<<(N_NODES + 255) / 256, 256, 0, stream>>>(cnt, N_NODES);

  // ---- layer 0: BN + ReLU ----
  col_stats<<<(N_NODES + 79) / 80, FIN, 0, stream>>>(x, N_NODES, FIN, 80, sums);
  finalize_stats<<<1, FIN, 0, stream>>>(sums, gamma0, beta0, ab, FIN, 1.0f / N_NODES);
  bn_relu<<<2048, 256, 0, stream>>>(x, h0, (long)N_NODES * FIN, FIN - 1, ab, FIN);

  // ---- layer 0: mean aggregation ----
  scatter_add<<<65536, 256, 0, stream>>>(h0, src, dst, N_EDGES, FIN, agg0);
  mean_scale<<<2048, 256, 0, stream>>>(agg0, cnt, (long)N_NODES * FIN, 8);

  // ---- layer 0: h1 = agg0@W0l + h0@W0r + bias0 ----
  gemm64x64<true, false><<<dim3(FOUT / 64, (N_NODES + 63) / 64), 256, 0, stream>>>(
      agg0, W0l, h0, W0r, bias0, h1, N_NODES, FIN, FOUT);

  // ---- layer 1: BN + ReLU (in place on h1) ----
  hipMemsetAsync(sums, 0, 2 * FOUT * 4, stream);
  col_stats<<<(N_NODES + 79) / 80, FOUT, 0, stream>>>(h1, N_NODES, FOUT, 80, sums);
  finalize_stats<<<1, FOUT, 0, stream>>>(sums, gamma1, beta1, ab, FOUT, 1.0f / N_NODES);
  bn_relu<<<4096, 256, 0, stream>>>(h1, h1, (long)N_NODES * FOUT, FOUT - 1, ab, FOUT);

  // ---- layer 1: mean aggregation ----
  scatter_add<<<65536, 256, 0, stream>>>(h1, src, dst, N_EDGES, FOUT, agg1);
  mean_scale<<<4096, 256, 0, stream>>>(agg1, cnt, (long)N_NODES * FOUT, 9);

  // ---- shortcut: out = x@Wsc + bsc ----
  gemm64x64<false, false><<<dim3(FOUT / 64, (N_NODES + 63) / 64), 256, 0, stream>>>(
      x, Wsc, nullptr, nullptr, bsc, out, N_NODES, FIN, FOUT);

  // ---- layer 1 GEMM accumulated into out ----
  gemm64x64<true, true><<<dim3(FOUT / 64, (N_NODES + 63) / 64), 256, 0, stream>>>(
      agg1, W1l, h1, W1r, bias1, out, N_NODES, FOUT, FOUT);
}

// Round 2
// 509.444 us; speedup vs baseline: 2.2224x; 2.2224x over previous
//
#include <hip/hip_runtime.h>
#include <cstdint>
#include <cstddef>

#define N_NODES 10000
#define N_EDGES 320000
#define FIN 256
#define FOUT 512
#define BN_EPS 1e-5f

// ---------------- BN column stats: sums[c]=sum, sums[F+c]=sumsq ----------------
__global__ void col_stats(const float* __restrict__ X, int nrows, int F,
                          int rows_per_blk, float* __restrict__ sums) {
  int c = threadIdx.x;  // blockDim.x == F
  int r0 = blockIdx.x * rows_per_blk;
  int r1 = min(r0 + rows_per_blk, nrows);
  float s = 0.f, q = 0.f;
  for (int r = r0; r < r1; ++r) {
    float v = X[(size_t)r * F + c];
    s += v;
    q = fmaf(v, v, q);
  }
  atomicAdd(&sums[c], s);
  atomicAdd(&sums[F + c], q);
}

// ---------------- finalize: ab[c] = scale, ab[F+c] = shift ----------------
__global__ void finalize_stats(const float* __restrict__ sums,
                               const float* __restrict__ gamma,
                               const float* __restrict__ beta,
                               float* __restrict__ ab, int F, float invN) {
  int c = blockIdx.x * blockDim.x + threadIdx.x;
  if (c < F) {
    float mu = sums[c] * invN;
    float var = fmaf(-mu, mu, sums[F + c] * invN);  // E[x^2]-mu^2 (biased)
    float s = rsqrtf(var + BN_EPS) * gamma[c];
    ab[c] = s;
    ab[F + c] = fmaf(-mu, s, beta[c]);
  }
}

// ---------------- apply BN + ReLU (elementwise) ----------------
__global__ void bn_relu(const float* __restrict__ X, float* __restrict__ H,
                        long total, int mask, const float* __restrict__ ab, int F) {
  long i = (long)blockIdx.x * blockDim.x + threadIdx.x;
  long stride = (long)gridDim.x * blockDim.x;
  for (; i < total; i += stride) {
    int c = (int)(i & mask);
    float v = fmaf(X[i], ab[c], ab[F + c]);
    H[i] = v > 0.f ? v : 0.f;
  }
}

// ---------------- int degree histogram ----------------
__global__ void edge_count(const int* __restrict__ dst, int E, int* __restrict__ deg) {
  int i = blockIdx.x * blockDim.x + threadIdx.x;
  if (i < E) atomicAdd(&deg[dst[i]], 1);
}

// ---------------- rowptr exclusive scan + icnt (single block, 1024 thr) ----------------
__global__ __launch_bounds__(1024)
void build_rowptr(const int* __restrict__ deg, int* __restrict__ rowptr,
                  float* __restrict__ icnt, int n) {
  __shared__ int part[1024];
  int tid = threadIdx.x;
  int chunk = (n + 1023) / 1024;
  int i0 = tid * chunk;
  int i1 = min(i0 + chunk, n);
  int s = 0;
  for (int i = i0; i < i1; ++i) s += deg[i];
  part[tid] = s;
  __syncthreads();
  // Hillis-Steele inclusive scan over 1024 partials
  for (int off = 1; off < 1024; off <<= 1) {
    int v = (tid >= off) ? part[tid - off] : 0;
    __syncthreads();
    part[tid] += v;
    __syncthreads();
  }
  int run = part[tid] - s;  // exclusive prefix for this thread's chunk
  for (int i = i0; i < i1; ++i) {
    int d = deg[i];
    rowptr[i] = run;
    icnt[i] = 1.0f / fmaxf((float)d, 1.0f);
    run += d;
  }
  if (tid == 1023) rowptr[n] = run;
}

// ---------------- bucket fill: csrc[] = src ids grouped by dst ----------------
__global__ void csr_fill(const int* __restrict__ src, const int* __restrict__ dst,
                         int E, const int* __restrict__ rowptr,
                         int* __restrict__ fill, int* __restrict__ csrc) {
  int e = blockIdx.x * blockDim.x + threadIdx.x;
  if (e < E) {
    int d = dst[e];
    int pos = rowptr[d] + atomicAdd(&fill[d], 1);
    csrc[pos] = src[e];
  }
}

// ---------------- gather-mean: agg[i] = mean_{j->i} H[j] ----------------
// One block per node. NT lanes * float4 = F channels. Single output write.
template <int F, int NT>
__global__ __launch_bounds__(NT)
void gather_mean(const float* __restrict__ H, const int* __restrict__ rowptr,
                 const int* __restrict__ csrc, const float* __restrict__ icnt,
                 float* __restrict__ agg) {
  int node = blockIdx.x;
  int c4 = threadIdx.x * 4;
  int beg = rowptr[node], end = rowptr[node + 1];
  float4 acc = make_float4(0.f, 0.f, 0.f, 0.f);
  int e = beg;
  // 2-deep unroll for latency hiding
  for (; e + 2 <= end; e += 2) {
    int s0 = csrc[e], s1 = csrc[e + 1];
    float4 a = *(const float4*)&H[(size_t)s0 * F + c4];
    float4 b = *(const float4*)&H[(size_t)s1 * F + c4];
    acc.x += a.x + b.x;
    acc.y += a.y + b.y;
    acc.z += a.z + b.z;
    acc.w += a.w + b.w;
  }
  if (e < end) {
    int s0 = csrc[e];
    float4 a = *(const float4*)&H[(size_t)s0 * F + c4];
    acc.x += a.x; acc.y += a.y; acc.z += a.z; acc.w += a.w;
  }
  float ic = icnt[node];
  acc.x *= ic; acc.y *= ic; acc.z *= ic; acc.w *= ic;
  *(float4*)&agg[(size_t)node * F + c4] = acc;
}

// ---------------- tiled fp32 GEMM: C = A1@W1 (+ A2@W2) + bias (+ C) ----------------
// A row-major [M,K], W row-major [K,Nc], C [M,Nc]. 64x64 tile, BK=16, 4x4/thread.
template <bool DUAL, bool ACC>
__global__ __launch_bounds__(256)
void gemm64x64(const float* __restrict__ A1, const float* __restrict__ W1,
               const float* __restrict__ A2, const float* __restrict__ W2,
               const float* __restrict__ bias, float* __restrict__ C,
               int M, int K, int Nc) {
  const int BK = 16;
  __shared__ float As1[BK][68];
  __shared__ float Ws1[BK][64];
  __shared__ float As2[DUAL ? BK : 1][68];
  __shared__ float Ws2[DUAL ? BK : 1][64];

  int tid = threadIdx.x;
  int tx = tid & 15, ty = tid >> 4;
  int m0 = blockIdx.y * 64;
  int n0 = blockIdx.x * 64;

  int la_m = tid >> 2;         // 0..63
  int la_k = (tid & 3) * 4;    // 0,4,8,12
  int lw_k = tid >> 4;         // 0..15
  int lw_n = (tid & 15) * 4;   // 0..60

  float acc[4][4] = {};

  for (int k0 = 0; k0 < K; k0 += BK) {
    int gr = m0 + la_m;
    float4 a4 = make_float4(0.f, 0.f, 0.f, 0.f);
    if (gr < M) a4 = *(const float4*)&A1[(size_t)gr * K + k0 + la_k];
    As1[la_k + 0][la_m] = a4.x;
    As1[la_k + 1][la_m] = a4.y;
    As1[la_k + 2][la_m] = a4.z;
    As1[la_k + 3][la_m] = a4.w;
    if constexpr (DUAL) {
      float4 c4 = make_float4(0.f, 0.f, 0.f, 0.f);
      if (gr < M) c4 = *(const float4*)&A2[(size_t)gr * K + k0 + la_k];
      As2[la_k + 0][la_m] = c4.x;
      As2[la_k + 1][la_m] = c4.y;
      As2[la_k + 2][la_m] = c4.z;
      As2[la_k + 3][la_m] = c4.w;
    }
    *(float4*)&Ws1[lw_k][lw_n] = *(const float4*)&W1[(size_t)(k0 + lw_k) * Nc + n0 + lw_n];
    if constexpr (DUAL) {
      *(float4*)&Ws2[lw_k][lw_n] = *(const float4*)&W2[(size_t)(k0 + lw_k) * Nc + n0 + lw_n];
    }
    __syncthreads();

#pragma unroll
    for (int kk = 0; kk < BK; ++kk) {
      float4 a1 = *(const float4*)&As1[kk][ty * 4];
      float4 b1 = *(const float4*)&Ws1[kk][tx * 4];
      float av[4] = {a1.x, a1.y, a1.z, a1.w};
      float bv[4] = {b1.x, b1.y, b1.z, b1.w};
#pragma unroll
      for (int i = 0; i < 4; ++i)
#pragma unroll
        for (int j = 0; j < 4; ++j) acc[i][j] = fmaf(av[i], bv[j], acc[i][j]);
      if constexpr (DUAL) {
        float4 a2 = *(const float4*)&As2[kk][ty * 4];
        float4 b2 = *(const float4*)&Ws2[kk][tx * 4];
        float av2[4] = {a2.x, a2.y, a2.z, a2.w};
        float bv2[4] = {b2.x, b2.y, b2.z, b2.w};
#pragma unroll
        for (int i = 0; i < 4; ++i)
#pragma unroll
          for (int j = 0; j < 4; ++j) acc[i][j] = fmaf(av2[i], bv2[j], acc[i][j]);
      }
    }
    __syncthreads();
  }

  float4 bv = *(const float4*)&bias[n0 + tx * 4];
#pragma unroll
  for (int i = 0; i < 4; ++i) {
    int r = m0 + ty * 4 + i;
    if (r < M) {
      float* cp = &C[(size_t)r * Nc + n0 + tx * 4];
      float4 o;
      o.x = acc[i][0] + bv.x;
      o.y = acc[i][1] + bv.y;
      o.z = acc[i][2] + bv.z;
      o.w = acc[i][3] + bv.w;
      if constexpr (ACC) {
        float4 old = *(const float4*)cp;
        o.x += old.x; o.y += old.y; o.z += old.z; o.w += old.w;
      }
      *(float4*)cp = o;
    }
  }
}

extern "C" void kernel_launch(void* const* d_in, const int* in_sizes, int n_in,
                              void* d_out, int out_size, void* d_ws, size_t ws_size,
                              hipStream_t stream) {
  const float* x = (const float*)d_in[0];
  const int* ei = (const int*)d_in[1];
  const int* src = ei;
  const int* dst = ei + N_EDGES;
  const float* gamma0 = (const float*)d_in[2];
  const float* beta0  = (const float*)d_in[3];
  const float* W0l    = (const float*)d_in[4];
  const float* W0r    = (const float*)d_in[5];
  const float* bias0  = (const float*)d_in[6];
  const float* gamma1 = (const float*)d_in[7];
  const float* beta1  = (const float*)d_in[8];
  const float* W1l    = (const float*)d_in[9];
  const float* W1r    = (const float*)d_in[10];
  const float* bias1  = (const float*)d_in[11];
  const float* Wsc    = (const float*)d_in[12];
  const float* bsc    = (const float*)d_in[13];
  float* out = (float*)d_out;

  float* p = (float*)d_ws;
  float* h0   = p; p += (size_t)N_NODES * FIN;   // BN0+ReLU output
  float* agg0 = p; p += (size_t)N_NODES * FIN;   // layer0 mean-agg
  float* h1   = p; p += (size_t)N_NODES * FOUT;  // SAGE0 out -> BN1+ReLU in place
  float* agg1 = p; p += (size_t)N_NODES * FOUT;  // layer1 mean-agg
  float* icnt = p; p += N_NODES;                 // 1/max(deg,1)
  float* sums = p; p += 2 * FOUT;                // col sums / sumsq
  float* ab   = p; p += 2 * FOUT;                // BN scale / shift
  int* ip = (int*)p;
  int* deg    = ip; ip += N_NODES;               // int degrees (zeroed)
  int* fill   = ip; ip += N_NODES;               // bucket cursors (zeroed)
  int* rowptr = ip; ip += N_NODES + 1;           // CSR offsets
  int* csrc   = ip; ip += N_EDGES;               // src ids grouped by dst

  // zero only what must start at 0: sums, deg, fill (contiguous-ish regions)
  hipMemsetAsync(sums, 0, 2 * FOUT * sizeof(float), stream);
  hipMemsetAsync(deg, 0, 2 * N_NODES * sizeof(int), stream);  // deg + fill

  // ---- CSR build (shared by both layers) ----
  edge_count<<<(N_EDGES + 255) / 256, 256, 0, stream>>>(dst, N_EDGES, deg);
  build_rowptr<<<1, 1024, 0, stream>>>(deg, rowptr, icnt, N_NODES);
  csr_fill<<<(N_EDGES + 255) / 256, 256, 0, stream>>>(src, dst, N_EDGES, rowptr, fill, csrc);

  // ---- layer 0: BN + ReLU ----
  col_stats<<<(N_NODES + 79) / 80, FIN, 0, stream>>>(x, N_NODES, FIN, 80, sums);
  finalize_stats<<<1, FIN, 0, stream>>>(sums, gamma0, beta0, ab, FIN, 1.0f / N_NODES);
  bn_relu<<<2048, 256, 0, stream>>>(x, h0, (long)N_NODES * FIN, FIN - 1, ab, FIN);

  // ---- layer 0: mean aggregation (gather, no atomics) ----
  gather_mean<FIN, FIN / 4><<<N_NODES, FIN / 4, 0, stream>>>(h0, rowptr, csrc, icnt, agg0);

  // ---- layer 0: h1 = agg0@W0l + h0@W0r + bias0 ----
  gemm64x64<true, false><<<dim3(FOUT / 64, (N_NODES + 63) / 64), 256, 0, stream>>>(
      agg0, W0l, h0, W0r, bias0, h1, N_NODES, FIN, FOUT);

  // ---- layer 1: BN + ReLU (in place on h1) ----
  hipMemsetAsync(sums, 0, 2 * FOUT * sizeof(float), stream);
  col_stats<<<(N_NODES + 79) / 80, FOUT, 0, stream>>>(h1, N_NODES, FOUT, 80, sums);
  finalize_stats<<<1, FOUT, 0, stream>>>(sums, gamma1, beta1, ab, FOUT, 1.0f / N_NODES);
  bn_relu<<<4096, 256, 0, stream>>>(h1, h1, (long)N_NODES * FOUT, FOUT - 1, ab, FOUT);

  // ---- layer 1: mean aggregation ----
  gather_mean<FOUT, FOUT / 4><<<N_NODES, FOUT / 4, 0, stream>>>(h1, rowptr, csrc, icnt, agg1);

  // ---- shortcut: out = x@Wsc + bsc ----
  gemm64x64<false, false><<<dim3(FOUT / 64, (N_NODES + 63) / 64), 256, 0, stream>>>(
      x, Wsc, nullptr, nullptr, bsc, out, N_NODES, FIN, FOUT);

  // ---- layer 1 GEMM accumulated into out ----
  gemm64x64<true, true><<<dim3(FOUT / 64, (N_NODES + 63) / 64), 256, 0, stream>>>(
      agg1, W1l, h1, W1r, bias1, out, N_NODES, FOUT, FOUT);
}

// Round 3
// 294.464 us; speedup vs baseline: 3.8449x; 1.7301x over previous
//
#include <hip/hip_runtime.h>
#include <hip/hip_bf16.h>
#include <cstdint>
#include <cstddef>

#define N_NODES 10000
#define N_EDGES 320000
#define FIN 256
#define FOUT 512
#define BN_EPS 1e-5f

typedef unsigned short ushort_t;
typedef __attribute__((ext_vector_type(8))) short short8;
typedef __attribute__((ext_vector_type(4))) float f32x4;
typedef __attribute__((ext_vector_type(4))) unsigned short ushort4v;
typedef __attribute__((ext_vector_type(8))) unsigned short ushort8v;

__device__ inline ushort_t f2bf(float f) {
  __hip_bfloat16 h = __float2bfloat16(f);  // RNE
  return *reinterpret_cast<ushort_t*>(&h);
}
__device__ inline float bf2f(ushort_t u) {
  unsigned int v = ((unsigned int)u) << 16;
  union { unsigned int i; float f; } c;
  c.i = v;
  return c.f;
}

// ---------------- BN column stats (fp32 input) ----------------
__global__ void col_stats_f(const float* __restrict__ X, int nrows, int F,
                            int rows_per_blk, float* __restrict__ sums) {
  int c = threadIdx.x;
  int r0 = blockIdx.x * rows_per_blk;
  int r1 = min(r0 + rows_per_blk, nrows);
  float s = 0.f, q = 0.f;
  for (int r = r0; r < r1; ++r) {
    float v = X[(size_t)r * F + c];
    s += v;
    q = fmaf(v, v, q);
  }
  atomicAdd(&sums[c], s);
  atomicAdd(&sums[F + c], q);
}

// ---------------- BN column stats (bf16 input) ----------------
__global__ void col_stats_b(const ushort_t* __restrict__ X, int nrows, int F,
                            int rows_per_blk, float* __restrict__ sums) {
  int c = threadIdx.x;
  int r0 = blockIdx.x * rows_per_blk;
  int r1 = min(r0 + rows_per_blk, nrows);
  float s = 0.f, q = 0.f;
  for (int r = r0; r < r1; ++r) {
    float v = bf2f(X[(size_t)r * F + c]);
    s += v;
    q = fmaf(v, v, q);
  }
  atomicAdd(&sums[c], s);
  atomicAdd(&sums[F + c], q);
}

// ---------------- finalize: ab[c] = scale, ab[F+c] = shift ----------------
__global__ void finalize_stats(const float* __restrict__ sums,
                               const float* __restrict__ gamma,
                               const float* __restrict__ beta,
                               float* __restrict__ ab, int F, float invN) {
  int c = blockIdx.x * blockDim.x + threadIdx.x;
  if (c < F) {
    float mu = sums[c] * invN;
    float var = fmaf(-mu, mu, sums[F + c] * invN);
    float s = rsqrtf(var + BN_EPS) * gamma[c];
    ab[c] = s;
    ab[F + c] = fmaf(-mu, s, beta[c]);
  }
}

// ---------------- BN+ReLU: fp32 in -> bf16 out (4 elems/thread) ----------------
__global__ void bn_relu_f2b(const float* __restrict__ X, ushort_t* __restrict__ H,
                            long total4, int mask, const float* __restrict__ ab, int F) {
  long i = (long)blockIdx.x * blockDim.x + threadIdx.x;
  if (i >= total4) return;
  long i0 = i * 4;
  float4 v = *(const float4*)&X[i0];
  int c = (int)(i0 & mask);
  ushort4v o;
  float r0 = fmaf(v.x, ab[c + 0], ab[F + c + 0]);
  float r1 = fmaf(v.y, ab[c + 1], ab[F + c + 1]);
  float r2 = fmaf(v.z, ab[c + 2], ab[F + c + 2]);
  float r3 = fmaf(v.w, ab[c + 3], ab[F + c + 3]);
  o.x = f2bf(fmaxf(r0, 0.f));
  o.y = f2bf(fmaxf(r1, 0.f));
  o.z = f2bf(fmaxf(r2, 0.f));
  o.w = f2bf(fmaxf(r3, 0.f));
  *(ushort4v*)&H[i0] = o;
}

// ---------------- BN+ReLU: bf16 in -> bf16 out ----------------
__global__ void bn_relu_b2b(const ushort_t* __restrict__ X, ushort_t* __restrict__ H,
                            long total4, int mask, const float* __restrict__ ab, int F) {
  long i = (long)blockIdx.x * blockDim.x + threadIdx.x;
  if (i >= total4) return;
  long i0 = i * 4;
  ushort4v v = *(const ushort4v*)&X[i0];
  int c = (int)(i0 & mask);
  ushort4v o;
  float r0 = fmaf(bf2f(v.x), ab[c + 0], ab[F + c + 0]);
  float r1 = fmaf(bf2f(v.y), ab[c + 1], ab[F + c + 1]);
  float r2 = fmaf(bf2f(v.z), ab[c + 2], ab[F + c + 2]);
  float r3 = fmaf(bf2f(v.w), ab[c + 3], ab[F + c + 3]);
  o.x = f2bf(fmaxf(r0, 0.f));
  o.y = f2bf(fmaxf(r1, 0.f));
  o.z = f2bf(fmaxf(r2, 0.f));
  o.w = f2bf(fmaxf(r3, 0.f));
  *(ushort4v*)&H[i0] = o;
}

// ---------------- fp32 -> bf16 copy (4 elems/thread) ----------------
__global__ void f2b_copy(const float* __restrict__ X, ushort_t* __restrict__ Y, long total4) {
  long i = (long)blockIdx.x * blockDim.x + threadIdx.x;
  if (i >= total4) return;
  long i0 = i * 4;
  float4 v = *(const float4*)&X[i0];
  ushort4v o;
  o.x = f2bf(v.x); o.y = f2bf(v.y); o.z = f2bf(v.z); o.w = f2bf(v.w);
  *(ushort4v*)&Y[i0] = o;
}

// ---------------- transpose + convert: W[K][N] fp32 -> Wt[N][K] bf16 ----------------
__global__ __launch_bounds__(256)
void transpose_f2b(const float* __restrict__ W, ushort_t* __restrict__ Wt, int K, int N) {
  __shared__ ushort_t t[32][40];
  int bk = blockIdx.x * 32, bn = blockIdx.y * 32;
  int tx = threadIdx.x & 31, ty = threadIdx.x >> 5;  // 32 x 8
#pragma unroll
  for (int i = 0; i < 4; ++i)
    t[ty + i * 8][tx] = f2bf(W[(size_t)(bk + ty + i * 8) * N + bn + tx]);
  __syncthreads();
#pragma unroll
  for (int i = 0; i < 4; ++i)
    Wt[(size_t)(bn + ty + i * 8) * K + bk + tx] = t[tx][ty + i * 8];
}

// ---------------- int degree histogram ----------------
__global__ void edge_count(const int* __restrict__ dst, int E, int* __restrict__ deg) {
  int i = blockIdx.x * blockDim.x + threadIdx.x;
  if (i < E) atomicAdd(&deg[dst[i]], 1);
}

// ---------------- rowptr exclusive scan + icnt ----------------
__global__ __launch_bounds__(1024)
void build_rowptr(const int* __restrict__ deg, int* __restrict__ rowptr,
                  float* __restrict__ icnt, int n) {
  __shared__ int part[1024];
  int tid = threadIdx.x;
  int chunk = (n + 1023) / 1024;
  int i0 = tid * chunk;
  int i1 = min(i0 + chunk, n);
  int s = 0;
  for (int i = i0; i < i1; ++i) s += deg[i];
  part[tid] = s;
  __syncthreads();
  for (int off = 1; off < 1024; off <<= 1) {
    int v = (tid >= off) ? part[tid - off] : 0;
    __syncthreads();
    part[tid] += v;
    __syncthreads();
  }
  int run = part[tid] - s;
  for (int i = i0; i < i1; ++i) {
    int d = deg[i];
    rowptr[i] = run;
    icnt[i] = 1.0f / fmaxf((float)d, 1.0f);
    run += d;
  }
  if (tid == 1023) rowptr[n] = run;
}

// ---------------- bucket fill ----------------
__global__ void csr_fill(const int* __restrict__ src, const int* __restrict__ dst,
                         int E, const int* __restrict__ rowptr,
                         int* __restrict__ fill, int* __restrict__ csrc) {
  int e = blockIdx.x * blockDim.x + threadIdx.x;
  if (e < E) {
    int d = dst[e];
    int pos = rowptr[d] + atomicAdd(&fill[d], 1);
    csrc[pos] = src[e];
  }
}

// ---------------- gather-mean, bf16 in/out, fp32 accumulate ----------------
template <int F>
__global__ __launch_bounds__(64)
void gather_mean_bf(const ushort_t* __restrict__ H, const int* __restrict__ rowptr,
                    const int* __restrict__ csrc, const float* __restrict__ icnt,
                    ushort_t* __restrict__ agg) {
  constexpr int VEC = F / 64;  // 4 or 8
  int node = blockIdx.x;
  int c0 = threadIdx.x * VEC;
  int beg = rowptr[node], end = rowptr[node + 1];
  float acc[VEC] = {};
  int e = beg;
  for (; e + 2 <= end; e += 2) {
    int s0 = csrc[e], s1 = csrc[e + 1];
    if constexpr (VEC == 8) {
      ushort8v a = *(const ushort8v*)&H[(size_t)s0 * F + c0];
      ushort8v b = *(const ushort8v*)&H[(size_t)s1 * F + c0];
#pragma unroll
      for (int j = 0; j < 8; ++j) acc[j] += bf2f(a[j]) + bf2f(b[j]);
    } else {
      ushort4v a = *(const ushort4v*)&H[(size_t)s0 * F + c0];
      ushort4v b = *(const ushort4v*)&H[(size_t)s1 * F + c0];
#pragma unroll
      for (int j = 0; j < 4; ++j) acc[j] += bf2f(a[j]) + bf2f(b[j]);
    }
  }
  if (e < end) {
    int s0 = csrc[e];
    if constexpr (VEC == 8) {
      ushort8v a = *(const ushort8v*)&H[(size_t)s0 * F + c0];
#pragma unroll
      for (int j = 0; j < 8; ++j) acc[j] += bf2f(a[j]);
    } else {
      ushort4v a = *(const ushort4v*)&H[(size_t)s0 * F + c0];
#pragma unroll
      for (int j = 0; j < 4; ++j) acc[j] += bf2f(a[j]);
    }
  }
  float ic = icnt[node];
  if constexpr (VEC == 8) {
    ushort8v o;
#pragma unroll
    for (int j = 0; j < 8; ++j) o[j] = f2bf(acc[j] * ic);
    *(ushort8v*)&agg[(size_t)node * F + c0] = o;
  } else {
    ushort4v o;
#pragma unroll
    for (int j = 0; j < 4; ++j) o[j] = f2bf(acc[j] * ic);
    *(ushort4v*)&agg[(size_t)node * F + c0] = o;
  }
}

// ---------------- MFMA bf16 GEMM: C = A1@B1^T + A2@B2^T + bias (+C) ----------------
// A row-major [M][K*] bf16; B* is Wt [512][K*] bf16 (N-major, k contiguous).
// 128x128 block tile, BK=64, 4 waves (2x2), each wave 64x64 via 4x4 mfma_16x16x32.
// EPI: 0 = store bf16, 1 = store f32, 2 = accumulate f32.
template <int EPI>
__global__ __launch_bounds__(256)
void gemm_mfma(const ushort_t* __restrict__ A1, const ushort_t* __restrict__ B1,
               const ushort_t* __restrict__ A2, const ushort_t* __restrict__ B2,
               int K1, int K2, const float* __restrict__ bias,
               void* __restrict__ Cv, int M) {
  __shared__ __align__(16) short As[128][72];
  __shared__ __align__(16) short Bs[128][72];

  int tid = threadIdx.x;
  int lane = tid & 63;
  int w = tid >> 6;
  int wm = w >> 1, wn = w & 1;
  int m0 = blockIdx.y * 128;
  int n0 = blockIdx.x * 128;

  int srow = tid >> 1;            // 0..127
  int shalf = (tid & 1) * 32;     // 0 or 32 (k elems)

  f32x4 acc[4][4] = {};

  int Ktot = K1 + K2;
  for (int k0 = 0; k0 < Ktot; k0 += 64) {
    const ushort_t* Asrc;
    const ushort_t* Bsrc;
    int kk0, KA;
    if (k0 < K1) { Asrc = A1; Bsrc = B1; kk0 = k0; KA = K1; }
    else         { Asrc = A2; Bsrc = B2; kk0 = k0 - K1; KA = K2; }

    int gr = m0 + srow;
    if (gr < M) {
      const short8* ap = (const short8*)&Asrc[(size_t)gr * KA + kk0 + shalf];
#pragma unroll
      for (int j = 0; j < 4; ++j) *(short8*)&As[srow][shalf + j * 8] = ap[j];
    } else {
      short8 z = {};
#pragma unroll
      for (int j = 0; j < 4; ++j) *(short8*)&As[srow][shalf + j * 8] = z;
    }
    const short8* bp = (const short8*)&Bsrc[(size_t)(n0 + srow) * KA + kk0 + shalf];
#pragma unroll
    for (int j = 0; j < 4; ++j) *(short8*)&Bs[srow][shalf + j * 8] = bp[j];
    __syncthreads();

#pragma unroll
    for (int ks = 0; ks < 2; ++ks) {
      int kof = ks * 32 + (lane >> 4) * 8;
      int rsel = lane & 15;
      short8 af[4], bfv[4];
#pragma unroll
      for (int mi = 0; mi < 4; ++mi)
        af[mi] = *(const short8*)&As[wm * 64 + mi * 16 + rsel][kof];
#pragma unroll
      for (int ni = 0; ni < 4; ++ni)
        bfv[ni] = *(const short8*)&Bs[wn * 64 + ni * 16 + rsel][kof];
#pragma unroll
      for (int mi = 0; mi < 4; ++mi)
#pragma unroll
        for (int ni = 0; ni < 4; ++ni)
          acc[mi][ni] = __builtin_amdgcn_mfma_f32_16x16x32_bf16(af[mi], bfv[ni], acc[mi][ni], 0, 0, 0);
    }
    __syncthreads();
  }

  // epilogue: D row = (lane>>4)*4 + reg, col = lane&15  [m89/m91 layout]
  int colbase = n0 + wn * 64 + (lane & 15);
  int rowq = (lane >> 4) * 4;
#pragma unroll
  for (int ni = 0; ni < 4; ++ni) {
    int col = colbase + ni * 16;
    float bv = bias[col];
#pragma unroll
    for (int mi = 0; mi < 4; ++mi) {
      int rbase = m0 + wm * 64 + mi * 16 + rowq;
#pragma unroll
      for (int r = 0; r < 4; ++r) {
        int row = rbase + r;
        if (row < M) {
          float v = acc[mi][ni][r] + bv;
          if constexpr (EPI == 0) {
            ((ushort_t*)Cv)[(size_t)row * 512 + col] = f2bf(v);
          } else if constexpr (EPI == 1) {
            ((float*)Cv)[(size_t)row * 512 + col] = v;
          } else {
            float* cp = &((float*)Cv)[(size_t)row * 512 + col];
            *cp = *cp + v;
          }
        }
      }
    }
  }
}

extern "C" void kernel_launch(void* const* d_in, const int* in_sizes, int n_in,
                              void* d_out, int out_size, void* d_ws, size_t ws_size,
                              hipStream_t stream) {
  const float* x = (const float*)d_in[0];
  const int* ei = (const int*)d_in[1];
  const int* src = ei;
  const int* dst = ei + N_EDGES;
  const float* gamma0 = (const float*)d_in[2];
  const float* beta0  = (const float*)d_in[3];
  const float* W0l    = (const float*)d_in[4];
  const float* W0r    = (const float*)d_in[5];
  const float* bias0  = (const float*)d_in[6];
  const float* gamma1 = (const float*)d_in[7];
  const float* beta1  = (const float*)d_in[8];
  const float* W1l    = (const float*)d_in[9];
  const float* W1r    = (const float*)d_in[10];
  const float* bias1  = (const float*)d_in[11];
  const float* Wsc    = (const float*)d_in[12];
  const float* bsc    = (const float*)d_in[13];
  float* out = (float*)d_out;

  char* wp = (char*)d_ws;
  ushort_t* h0b   = (ushort_t*)wp; wp += (size_t)N_NODES * FIN * 2;
  ushort_t* agg0b = (ushort_t*)wp; wp += (size_t)N_NODES * FIN * 2;
  ushort_t* h1b   = (ushort_t*)wp; wp += (size_t)N_NODES * FOUT * 2;
  ushort_t* h1rb  = (ushort_t*)wp; wp += (size_t)N_NODES * FOUT * 2;
  ushort_t* agg1b = (ushort_t*)wp; wp += (size_t)N_NODES * FOUT * 2;
  ushort_t* xb    = (ushort_t*)wp; wp += (size_t)N_NODES * FIN * 2;
  ushort_t* w0lt  = (ushort_t*)wp; wp += (size_t)FIN * FOUT * 2;   // [512][256]
  ushort_t* w0rt  = (ushort_t*)wp; wp += (size_t)FIN * FOUT * 2;
  ushort_t* wsct  = (ushort_t*)wp; wp += (size_t)FIN * FOUT * 2;
  ushort_t* w1lt  = (ushort_t*)wp; wp += (size_t)FOUT * FOUT * 2;  // [512][512]
  ushort_t* w1rt  = (ushort_t*)wp; wp += (size_t)FOUT * FOUT * 2;
  float* icnt = (float*)wp; wp += (size_t)N_NODES * 4;
  float* sums = (float*)wp; wp += 2 * FOUT * 4;
  float* ab   = (float*)wp; wp += 2 * FOUT * 4;
  int* deg    = (int*)wp; wp += (size_t)N_NODES * 4;
  int* fill   = (int*)wp; wp += (size_t)N_NODES * 4;
  int* rowptr = (int*)wp; wp += (size_t)(N_NODES + 4) * 4;
  int* csrc   = (int*)wp; wp += (size_t)N_EDGES * 4;

  hipMemsetAsync(sums, 0, 2 * FOUT * sizeof(float), stream);
  hipMemsetAsync(deg, 0, 2 * N_NODES * sizeof(int), stream);  // deg + fill contiguous

  // ---- CSR build ----
  edge_count<<<(N_EDGES + 255) / 256, 256, 0, stream>>>(dst, N_EDGES, deg);
  build_rowptr<<<1, 1024, 0, stream>>>(deg, rowptr, icnt, N_NODES);
  csr_fill<<<(N_EDGES + 255) / 256, 256, 0, stream>>>(src, dst, N_EDGES, rowptr, fill, csrc);

  // ---- weight prep: transpose + bf16 ----
  transpose_f2b<<<dim3(FIN / 32, FOUT / 32), 256, 0, stream>>>(W0l, w0lt, FIN, FOUT);
  transpose_f2b<<<dim3(FIN / 32, FOUT / 32), 256, 0, stream>>>(W0r, w0rt, FIN, FOUT);
  transpose_f2b<<<dim3(FIN / 32, FOUT / 32), 256, 0, stream>>>(Wsc, wsct, FIN, FOUT);
  transpose_f2b<<<dim3(FOUT / 32, FOUT / 32), 256, 0, stream>>>(W1l, w1lt, FOUT, FOUT);
  transpose_f2b<<<dim3(FOUT / 32, FOUT / 32), 256, 0, stream>>>(W1r, w1rt, FOUT, FOUT);

  // ---- x -> bf16 (for shortcut GEMM) ----
  f2b_copy<<<(N_NODES * FIN / 4 + 255) / 256, 256, 0, stream>>>(x, xb, (long)N_NODES * FIN / 4);

  // ---- layer 0: BN + ReLU ----
  col_stats_f<<<N_NODES / 80, FIN, 0, stream>>>(x, N_NODES, FIN, 80, sums);
  finalize_stats<<<1, FIN, 0, stream>>>(sums, gamma0, beta0, ab, FIN, 1.0f / N_NODES);
  bn_relu_f2b<<<(N_NODES * FIN / 4 + 255) / 256, 256, 0, stream>>>(
      x, h0b, (long)N_NODES * FIN / 4, FIN - 1, ab, FIN);

  // ---- layer 0: gather mean ----
  gather_mean_bf<FIN><<<N_NODES, 64, 0, stream>>>(h0b, rowptr, csrc, icnt, agg0b);

  // ---- layer 0 GEMM: h1 = agg0@W0l + h0@W0r + bias0 (bf16 out) ----
  gemm_mfma<0><<<dim3(FOUT / 128, (N_NODES + 127) / 128), 256, 0, stream>>>(
      agg0b, w0lt, h0b, w0rt, FIN, FIN, bias0, h1b, N_NODES);

  // ---- layer 1: BN + ReLU ----
  hipMemsetAsync(sums, 0, 2 * FOUT * sizeof(float), stream);
  col_stats_b<<<N_NODES / 80, FOUT, 0, stream>>>(h1b, N_NODES, FOUT, 80, sums);
  finalize_stats<<<1, FOUT, 0, stream>>>(sums, gamma1, beta1, ab, FOUT, 1.0f / N_NODES);
  bn_relu_b2b<<<(N_NODES * FOUT / 4 + 255) / 256, 256, 0, stream>>>(
      h1b, h1rb, (long)N_NODES * FOUT / 4, FOUT - 1, ab, FOUT);

  // ---- layer 1: gather mean ----
  gather_mean_bf<FOUT><<<N_NODES, 64, 0, stream>>>(h1rb, rowptr, csrc, icnt, agg1b);

  // ---- shortcut: out = x@Wsc + bsc (f32 out) ----
  gemm_mfma<1><<<dim3(FOUT / 128, (N_NODES + 127) / 128), 256, 0, stream>>>(
      xb, wsct, nullptr, nullptr, FIN, 0, bsc, out, N_NODES);

  // ---- layer 1 GEMM: out += agg1@W1l + h1r@W1r + bias1 ----
  gemm_mfma<2><<<dim3(FOUT / 128, (N_NODES + 127) / 128), 256, 0, stream>>>(
      agg1b, w1lt, h1rb, w1rt, FOUT, FOUT, bias1, out, N_NODES);
}

// Round 4
// 266.030 us; speedup vs baseline: 4.2559x; 1.1069x over previous
//
#include <hip/hip_runtime.h>
#include <hip/hip_bf16.h>
#include <cstdint>
#include <cstddef>

#define N_NODES 10000
#define N_EDGES 320000
#define FIN 256
#define FOUT 512
#define BN_EPS 1e-5f

typedef unsigned short ushort_t;
typedef __attribute__((ext_vector_type(8))) short short8;
typedef __attribute__((ext_vector_type(4))) float f32x4;
typedef __attribute__((ext_vector_type(4))) unsigned short ushort4v;
typedef __attribute__((ext_vector_type(8))) unsigned short ushort8v;

__device__ inline ushort_t f2bf(float f) {
  __hip_bfloat16 h = __float2bfloat16(f);  // RNE
  return *reinterpret_cast<ushort_t*>(&h);
}
__device__ inline float bf2f(ushort_t u) {
  unsigned int v = ((unsigned int)u) << 16;
  union { unsigned int i; float f; } c;
  c.i = v;
  return c.f;
}

// ---------------- BN column stats (fp32 input) ----------------
__global__ void col_stats_f(const float* __restrict__ X, int nrows, int F,
                            int rows_per_blk, float* __restrict__ sums) {
  int c = threadIdx.x;
  int r0 = blockIdx.x * rows_per_blk;
  int r1 = min(r0 + rows_per_blk, nrows);
  float s = 0.f, q = 0.f;
  for (int r = r0; r < r1; ++r) {
    float v = X[(size_t)r * F + c];
    s += v;
    q = fmaf(v, v, q);
  }
  atomicAdd(&sums[c], s);
  atomicAdd(&sums[F + c], q);
}

// ---------------- BN column stats (bf16 input) ----------------
__global__ void col_stats_b(const ushort_t* __restrict__ X, int nrows, int F,
                            int rows_per_blk, float* __restrict__ sums) {
  int c = threadIdx.x;
  int r0 = blockIdx.x * rows_per_blk;
  int r1 = min(r0 + rows_per_blk, nrows);
  float s = 0.f, q = 0.f;
  for (int r = r0; r < r1; ++r) {
    float v = bf2f(X[(size_t)r * F + c]);
    s += v;
    q = fmaf(v, v, q);
  }
  atomicAdd(&sums[c], s);
  atomicAdd(&sums[F + c], q);
}

// ---------------- finalize: ab[c] = scale, ab[F+c] = shift ----------------
__global__ void finalize_stats(const float* __restrict__ sums,
                               const float* __restrict__ gamma,
                               const float* __restrict__ beta,
                               float* __restrict__ ab, int F, float invN) {
  int c = blockIdx.x * blockDim.x + threadIdx.x;
  if (c < F) {
    float mu = sums[c] * invN;
    float var = fmaf(-mu, mu, sums[F + c] * invN);
    float s = rsqrtf(var + BN_EPS) * gamma[c];
    ab[c] = s;
    ab[F + c] = fmaf(-mu, s, beta[c]);
  }
}

// ---------------- combined bias: o = a + b ----------------
__global__ void combine_bias(const float* __restrict__ a, const float* __restrict__ b,
                             float* __restrict__ o, int n) {
  int i = blockIdx.x * blockDim.x + threadIdx.x;
  if (i < n) o[i] = a[i] + b[i];
}

// ---------------- BN+ReLU: fp32 in -> bf16 out (4 elems/thread) ----------------
__global__ void bn_relu_f2b(const float* __restrict__ X, ushort_t* __restrict__ H,
                            long total4, int mask, const float* __restrict__ ab, int F) {
  long i = (long)blockIdx.x * blockDim.x + threadIdx.x;
  if (i >= total4) return;
  long i0 = i * 4;
  float4 v = *(const float4*)&X[i0];
  int c = (int)(i0 & mask);
  ushort4v o;
  o.x = f2bf(fmaxf(fmaf(v.x, ab[c + 0], ab[F + c + 0]), 0.f));
  o.y = f2bf(fmaxf(fmaf(v.y, ab[c + 1], ab[F + c + 1]), 0.f));
  o.z = f2bf(fmaxf(fmaf(v.z, ab[c + 2], ab[F + c + 2]), 0.f));
  o.w = f2bf(fmaxf(fmaf(v.w, ab[c + 3], ab[F + c + 3]), 0.f));
  *(ushort4v*)&H[i0] = o;
}

// ---------------- BN+ReLU: bf16 in -> bf16 out ----------------
__global__ void bn_relu_b2b(const ushort_t* __restrict__ X, ushort_t* __restrict__ H,
                            long total4, int mask, const float* __restrict__ ab, int F) {
  long i = (long)blockIdx.x * blockDim.x + threadIdx.x;
  if (i >= total4) return;
  long i0 = i * 4;
  ushort4v v = *(const ushort4v*)&X[i0];
  int c = (int)(i0 & mask);
  ushort4v o;
  o.x = f2bf(fmaxf(fmaf(bf2f(v.x), ab[c + 0], ab[F + c + 0]), 0.f));
  o.y = f2bf(fmaxf(fmaf(bf2f(v.y), ab[c + 1], ab[F + c + 1]), 0.f));
  o.z = f2bf(fmaxf(fmaf(bf2f(v.z), ab[c + 2], ab[F + c + 2]), 0.f));
  o.w = f2bf(fmaxf(fmaf(bf2f(v.w), ab[c + 3], ab[F + c + 3]), 0.f));
  *(ushort4v*)&H[i0] = o;
}

// ---------------- fp32 -> bf16 copy (4 elems/thread) ----------------
__global__ void f2b_copy(const float* __restrict__ X, ushort_t* __restrict__ Y, long total4) {
  long i = (long)blockIdx.x * blockDim.x + threadIdx.x;
  if (i >= total4) return;
  long i0 = i * 4;
  float4 v = *(const float4*)&X[i0];
  ushort4v o;
  o.x = f2bf(v.x); o.y = f2bf(v.y); o.z = f2bf(v.z); o.w = f2bf(v.w);
  *(ushort4v*)&Y[i0] = o;
}

// ---------------- transpose + convert: W[K][N] fp32 -> Wt[N][K] bf16 ----------------
__global__ __launch_bounds__(256)
void transpose_f2b(const float* __restrict__ W, ushort_t* __restrict__ Wt, int K, int N) {
  __shared__ ushort_t t[32][40];
  int bk = blockIdx.x * 32, bn = blockIdx.y * 32;
  int tx = threadIdx.x & 31, ty = threadIdx.x >> 5;  // 32 x 8
#pragma unroll
  for (int i = 0; i < 4; ++i)
    t[ty + i * 8][tx] = f2bf(W[(size_t)(bk + ty + i * 8) * N + bn + tx]);
  __syncthreads();
#pragma unroll
  for (int i = 0; i < 4; ++i)
    Wt[(size_t)(bn + ty + i * 8) * K + bk + tx] = t[tx][ty + i * 8];
}

// ---------------- int degree histogram ----------------
__global__ void edge_count(const int* __restrict__ dst, int E, int* __restrict__ deg) {
  int i = blockIdx.x * blockDim.x + threadIdx.x;
  if (i < E) atomicAdd(&deg[dst[i]], 1);
}

// ---------------- rowptr exclusive scan + icnt ----------------
__global__ __launch_bounds__(1024)
void build_rowptr(const int* __restrict__ deg, int* __restrict__ rowptr,
                  float* __restrict__ icnt, int n) {
  __shared__ int part[1024];
  int tid = threadIdx.x;
  int chunk = (n + 1023) / 1024;
  int i0 = tid * chunk;
  int i1 = min(i0 + chunk, n);
  int s = 0;
  for (int i = i0; i < i1; ++i) s += deg[i];
  part[tid] = s;
  __syncthreads();
  for (int off = 1; off < 1024; off <<= 1) {
    int v = (tid >= off) ? part[tid - off] : 0;
    __syncthreads();
    part[tid] += v;
    __syncthreads();
  }
  int run = part[tid] - s;
  for (int i = i0; i < i1; ++i) {
    int d = deg[i];
    rowptr[i] = run;
    icnt[i] = 1.0f / fmaxf((float)d, 1.0f);
    run += d;
  }
  if (tid == 1023) rowptr[n] = run;
}

// ---------------- bucket fill ----------------
__global__ void csr_fill(const int* __restrict__ src, const int* __restrict__ dst,
                         int E, const int* __restrict__ rowptr,
                         int* __restrict__ fill, int* __restrict__ csrc) {
  int e = blockIdx.x * blockDim.x + threadIdx.x;
  if (e < E) {
    int d = dst[e];
    int pos = rowptr[d] + atomicAdd(&fill[d], 1);
    csrc[pos] = src[e];
  }
}

// ---------------- gather-mean, bf16 in/out, fp32 accumulate ----------------
template <int F>
__global__ __launch_bounds__(64)
void gather_mean_bf(const ushort_t* __restrict__ H, const int* __restrict__ rowptr,
                    const int* __restrict__ csrc, const float* __restrict__ icnt,
                    ushort_t* __restrict__ agg) {
  constexpr int VEC = F / 64;  // 4 or 8
  int node = blockIdx.x;
  int c0 = threadIdx.x * VEC;
  int beg = rowptr[node], end = rowptr[node + 1];
  float acc[VEC] = {};
  int e = beg;
  for (; e + 2 <= end; e += 2) {
    int s0 = csrc[e], s1 = csrc[e + 1];
    if constexpr (VEC == 8) {
      ushort8v a = *(const ushort8v*)&H[(size_t)s0 * F + c0];
      ushort8v b = *(const ushort8v*)&H[(size_t)s1 * F + c0];
#pragma unroll
      for (int j = 0; j < 8; ++j) acc[j] += bf2f(a[j]) + bf2f(b[j]);
    } else {
      ushort4v a = *(const ushort4v*)&H[(size_t)s0 * F + c0];
      ushort4v b = *(const ushort4v*)&H[(size_t)s1 * F + c0];
#pragma unroll
      for (int j = 0; j < 4; ++j) acc[j] += bf2f(a[j]) + bf2f(b[j]);
    }
  }
  if (e < end) {
    int s0 = csrc[e];
    if constexpr (VEC == 8) {
      ushort8v a = *(const ushort8v*)&H[(size_t)s0 * F + c0];
#pragma unroll
      for (int j = 0; j < 8; ++j) acc[j] += bf2f(a[j]);
    } else {
      ushort4v a = *(const ushort4v*)&H[(size_t)s0 * F + c0];
#pragma unroll
      for (int j = 0; j < 4; ++j) acc[j] += bf2f(a[j]);
    }
  }
  float ic = icnt[node];
  if constexpr (VEC == 8) {
    ushort8v o;
#pragma unroll
    for (int j = 0; j < 8; ++j) o[j] = f2bf(acc[j] * ic);
    *(ushort8v*)&agg[(size_t)node * F + c0] = o;
  } else {
    ushort4v o;
#pragma unroll
    for (int j = 0; j < 4; ++j) o[j] = f2bf(acc[j] * ic);
    *(ushort4v*)&agg[(size_t)node * F + c0] = o;
  }
}

// ---------------- MFMA bf16 GEMM: C = sum_s As@Bs^T + bias ----------------
// Up to 3 K-segments with compile-time lengths (0 = absent).
// A row-major [M][K] bf16; B is Wt [512][K] bf16 (N-major, k contiguous).
// 64x128 block tile, BK=64, 4 waves (2x2), each wave 32x64 via 2x4 mfma_16x16x32.
// EPI: 0 = store bf16, 1 = store f32.
#define GEMM_SEG(Aseg, Bseg, KA)                                                   \
  for (int k0 = 0; k0 < (KA); k0 += 64) {                                          \
    int gr = m0 + ar;                                                              \
    if (gr < M) {                                                                  \
      const short8* ap = (const short8*)&(Aseg)[(size_t)gr * (KA) + k0 + aq];      \
      *(short8*)&As[ar][aq] = ap[0];                                               \
      *(short8*)&As[ar][aq + 8] = ap[1];                                           \
    } else {                                                                       \
      short8 z = {};                                                               \
      *(short8*)&As[ar][aq] = z;                                                   \
      *(short8*)&As[ar][aq + 8] = z;                                               \
    }                                                                              \
    const short8* bp = (const short8*)&(Bseg)[(size_t)(n0 + br) * (KA) + k0 + bh]; \
    *(short8*)&Bs[br][bh] = bp[0];                                                 \
    *(short8*)&Bs[br][bh + 8] = bp[1];                                             \
    *(short8*)&Bs[br][bh + 16] = bp[2];                                            \
    *(short8*)&Bs[br][bh + 24] = bp[3];                                            \
    __syncthreads();                                                               \
    _Pragma("unroll")                                                              \
    for (int ks = 0; ks < 2; ++ks) {                                               \
      int kof = ks * 32 + (lane >> 4) * 8;                                         \
      int rsel = lane & 15;                                                        \
      short8 af[2], bfv[4];                                                        \
      af[0] = *(const short8*)&As[wm * 32 + rsel][kof];                            \
      af[1] = *(const short8*)&As[wm * 32 + 16 + rsel][kof];                       \
      _Pragma("unroll")                                                            \
      for (int ni = 0; ni < 4; ++ni)                                               \
        bfv[ni] = *(const short8*)&Bs[wn * 64 + ni * 16 + rsel][kof];              \
      _Pragma("unroll")                                                            \
      for (int mi = 0; mi < 2; ++mi)                                               \
        _Pragma("unroll")                                                          \
        for (int ni = 0; ni < 4; ++ni)                                             \
          acc[mi][ni] = __builtin_amdgcn_mfma_f32_16x16x32_bf16(                   \
              af[mi], bfv[ni], acc[mi][ni], 0, 0, 0);                              \
    }                                                                              \
    __syncthreads();                                                               \
  }

template <int EPI, int K0, int K1, int K2>
__global__ __launch_bounds__(256)
void gemm_mfma(const ushort_t* __restrict__ A0, const ushort_t* __restrict__ B0,
               const ushort_t* __restrict__ A1p, const ushort_t* __restrict__ B1p,
               const ushort_t* __restrict__ A2p, const ushort_t* __restrict__ B2p,
               const float* __restrict__ bias, void* __restrict__ Cv, int M) {
  __shared__ __align__(16) short As[64][72];
  __shared__ __align__(16) short Bs[128][72];

  int tid = threadIdx.x;
  int lane = tid & 63;
  int w = tid >> 6;
  int wm = w >> 1, wn = w & 1;
  int m0 = blockIdx.y * 64;
  int n0 = blockIdx.x * 128;

  int ar = tid >> 2;            // A stage: row 0..63
  int aq = (tid & 3) * 16;      // A stage: 16-elem quarter
  int br = tid >> 1;            // B stage: row 0..127
  int bh = (tid & 1) * 32;      // B stage: 32-elem half

  f32x4 acc[2][4] = {};

  GEMM_SEG(A0, B0, K0)
  if constexpr (K1 > 0) { GEMM_SEG(A1p, B1p, K1) }
  if constexpr (K2 > 0) { GEMM_SEG(A2p, B2p, K2) }

  // epilogue: D row = (lane>>4)*4 + reg, col = lane&15  [m89/m91 layout]
  int colbase = n0 + wn * 64 + (lane & 15);
  int rowq = (lane >> 4) * 4;
#pragma unroll
  for (int ni = 0; ni < 4; ++ni) {
    int col = colbase + ni * 16;
    float bv = bias[col];
#pragma unroll
    for (int mi = 0; mi < 2; ++mi) {
      int rbase = m0 + wm * 32 + mi * 16 + rowq;
#pragma unroll
      for (int r = 0; r < 4; ++r) {
        int row = rbase + r;
        if (row < M) {
          float v = acc[mi][ni][r] + bv;
          if constexpr (EPI == 0) {
            ((ushort_t*)Cv)[(size_t)row * 512 + col] = f2bf(v);
          } else {
            ((float*)Cv)[(size_t)row * 512 + col] = v;
          }
        }
      }
    }
  }
}

extern "C" void kernel_launch(void* const* d_in, const int* in_sizes, int n_in,
                              void* d_out, int out_size, void* d_ws, size_t ws_size,
                              hipStream_t stream) {
  const float* x = (const float*)d_in[0];
  const int* ei = (const int*)d_in[1];
  const int* src = ei;
  const int* dst = ei + N_EDGES;
  const float* gamma0 = (const float*)d_in[2];
  const float* beta0  = (const float*)d_in[3];
  const float* W0l    = (const float*)d_in[4];
  const float* W0r    = (const float*)d_in[5];
  const float* bias0  = (const float*)d_in[6];
  const float* gamma1 = (const float*)d_in[7];
  const float* beta1  = (const float*)d_in[8];
  const float* W1l    = (const float*)d_in[9];
  const float* W1r    = (const float*)d_in[10];
  const float* bias1  = (const float*)d_in[11];
  const float* Wsc    = (const float*)d_in[12];
  const float* bsc    = (const float*)d_in[13];
  float* out = (float*)d_out;

  char* wp = (char*)d_ws;
  ushort_t* h0b   = (ushort_t*)wp; wp += (size_t)N_NODES * FIN * 2;
  ushort_t* agg0b = (ushort_t*)wp; wp += (size_t)N_NODES * FIN * 2;
  ushort_t* h1b   = (ushort_t*)wp; wp += (size_t)N_NODES * FOUT * 2;
  ushort_t* h1rb  = (ushort_t*)wp; wp += (size_t)N_NODES * FOUT * 2;
  ushort_t* agg1b = (ushort_t*)wp; wp += (size_t)N_NODES * FOUT * 2;
  ushort_t* xb    = (ushort_t*)wp; wp += (size_t)N_NODES * FIN * 2;
  ushort_t* w0lt  = (ushort_t*)wp; wp += (size_t)FIN * FOUT * 2;   // [512][256]
  ushort_t* w0rt  = (ushort_t*)wp; wp += (size_t)FIN * FOUT * 2;
  ushort_t* wsct  = (ushort_t*)wp; wp += (size_t)FIN * FOUT * 2;
  ushort_t* w1lt  = (ushort_t*)wp; wp += (size_t)FOUT * FOUT * 2;  // [512][512]
  ushort_t* w1rt  = (ushort_t*)wp; wp += (size_t)FOUT * FOUT * 2;
  float* icnt  = (float*)wp; wp += (size_t)N_NODES * 4;
  float* sums  = (float*)wp; wp += 2 * FOUT * 4;
  float* ab    = (float*)wp; wp += 2 * FOUT * 4;
  float* cbias = (float*)wp; wp += FOUT * 4;
  int* deg    = (int*)wp; wp += (size_t)N_NODES * 4;
  int* fill   = (int*)wp; wp += (size_t)N_NODES * 4;
  int* rowptr = (int*)wp; wp += (size_t)(N_NODES + 4) * 4;
  int* csrc   = (int*)wp; wp += (size_t)N_EDGES * 4;

  hipMemsetAsync(sums, 0, 2 * FOUT * sizeof(float), stream);
  hipMemsetAsync(deg, 0, 2 * N_NODES * sizeof(int), stream);  // deg + fill contiguous

  // ---- CSR build ----
  edge_count<<<(N_EDGES + 255) / 256, 256, 0, stream>>>(dst, N_EDGES, deg);
  build_rowptr<<<1, 1024, 0, stream>>>(deg, rowptr, icnt, N_NODES);
  csr_fill<<<(N_EDGES + 255) / 256, 256, 0, stream>>>(src, dst, N_EDGES, rowptr, fill, csrc);

  // ---- weight prep: transpose + bf16; combined bias for merged GEMM ----
  transpose_f2b<<<dim3(FIN / 32, FOUT / 32), 256, 0, stream>>>(W0l, w0lt, FIN, FOUT);
  transpose_f2b<<<dim3(FIN / 32, FOUT / 32), 256, 0, stream>>>(W0r, w0rt, FIN, FOUT);
  transpose_f2b<<<dim3(FIN / 32, FOUT / 32), 256, 0, stream>>>(Wsc, wsct, FIN, FOUT);
  transpose_f2b<<<dim3(FOUT / 32, FOUT / 32), 256, 0, stream>>>(W1l, w1lt, FOUT, FOUT);
  transpose_f2b<<<dim3(FOUT / 32, FOUT / 32), 256, 0, stream>>>(W1r, w1rt, FOUT, FOUT);
  combine_bias<<<2, 256, 0, stream>>>(bias1, bsc, cbias, FOUT);

  // ---- x -> bf16 (for shortcut segment) ----
  f2b_copy<<<(N_NODES * FIN / 4 + 255) / 256, 256, 0, stream>>>(x, xb, (long)N_NODES * FIN / 4);

  // ---- layer 0: BN + ReLU ----
  col_stats_f<<<N_NODES / 80, FIN, 0, stream>>>(x, N_NODES, FIN, 80, sums);
  finalize_stats<<<1, FIN, 0, stream>>>(sums, gamma0, beta0, ab, FIN, 1.0f / N_NODES);
  bn_relu_f2b<<<(N_NODES * FIN / 4 + 255) / 256, 256, 0, stream>>>(
      x, h0b, (long)N_NODES * FIN / 4, FIN - 1, ab, FIN);

  // ---- layer 0: gather mean ----
  gather_mean_bf<FIN><<<N_NODES, 64, 0, stream>>>(h0b, rowptr, csrc, icnt, agg0b);

  // ---- layer 0 GEMM: h1 = agg0@W0l + h0@W0r + bias0 (bf16 out) ----
  gemm_mfma<0, FIN, FIN, 0><<<dim3(FOUT / 128, (N_NODES + 63) / 64), 256, 0, stream>>>(
      agg0b, w0lt, h0b, w0rt, nullptr, nullptr, bias0, h1b, N_NODES);

  // ---- layer 1: BN + ReLU ----
  hipMemsetAsync(sums, 0, 2 * FOUT * sizeof(float), stream);
  col_stats_b<<<N_NODES / 80, FOUT, 0, stream>>>(h1b, N_NODES, FOUT, 80, sums);
  finalize_stats<<<1, FOUT, 0, stream>>>(sums, gamma1, beta1, ab, FOUT, 1.0f / N_NODES);
  bn_relu_b2b<<<(N_NODES * FOUT / 4 + 255) / 256, 256, 0, stream>>>(
      h1b, h1rb, (long)N_NODES * FOUT / 4, FOUT - 1, ab, FOUT);

  // ---- layer 1: gather mean ----
  gather_mean_bf<FOUT><<<N_NODES, 64, 0, stream>>>(h1rb, rowptr, csrc, icnt, agg1b);

  // ---- merged GEMM: out = agg1@W1l + h1r@W1r + x@Wsc + (bias1+bsc), f32 out ----
  gemm_mfma<1, FOUT, FOUT, FIN><<<dim3(FOUT / 128, (N_NODES + 63) / 64), 256, 0, stream>>>(
      agg1b, w1lt, h1rb, w1rt, xb, wsct, cbias, out, N_NODES);
}

// Round 5
// 204.008 us; speedup vs baseline: 5.5498x; 1.3040x over previous
//
#include <hip/hip_runtime.h>
#include <hip/hip_bf16.h>
#include <cstdint>
#include <cstddef>

#define N_NODES 10000
#define N_EDGES 320000
#define FIN 256
#define FOUT 512
#define BN_EPS 1e-5f
#define DEG_CAP 128   // max degree supported; Binomial(320k, 1e-4) max ~56 (11+ sigma margin)

typedef unsigned short ushort_t;
typedef __attribute__((ext_vector_type(8))) short short8;
typedef __attribute__((ext_vector_type(4))) float f32x4;
typedef __attribute__((ext_vector_type(4))) unsigned short ushort4v;
typedef __attribute__((ext_vector_type(8))) unsigned short ushort8v;

__device__ inline ushort_t f2bf(float f) {
  __hip_bfloat16 h = __float2bfloat16(f);  // RNE
  return *reinterpret_cast<ushort_t*>(&h);
}
__device__ inline float bf2f(ushort_t u) {
  union { unsigned int i; float f; } c;
  c.i = ((unsigned int)u) << 16;
  return c.f;
}

// ---------------- BN column stats (fp32 input), blockDim.x == F ----------------
__global__ void col_stats_f(const float* __restrict__ X, int nrows, int F,
                            int rows_per_blk, float* __restrict__ sums) {
  int c = threadIdx.x;
  int r0 = blockIdx.x * rows_per_blk;
  int r1 = min(r0 + rows_per_blk, nrows);
  float s = 0.f, q = 0.f;
  for (int r = r0; r < r1; ++r) {
    float v = X[(size_t)r * F + c];
    s += v;
    q = fmaf(v, v, q);
  }
  atomicAdd(&sums[c], s);
  atomicAdd(&sums[F + c], q);
}

// ---------------- BN column stats (bf16 input) ----------------
__global__ void col_stats_b(const ushort_t* __restrict__ X, int nrows, int F,
                            int rows_per_blk, float* __restrict__ sums) {
  int c = threadIdx.x;
  int r0 = blockIdx.x * rows_per_blk;
  int r1 = min(r0 + rows_per_blk, nrows);
  float s = 0.f, q = 0.f;
  for (int r = r0; r < r1; ++r) {
    float v = bf2f(X[(size_t)r * F + c]);
    s += v;
    q = fmaf(v, v, q);
  }
  atomicAdd(&sums[c], s);
  atomicAdd(&sums[F + c], q);
}

// ---------------- BN+ReLU, stats finalized inline. Optional raw-bf16 2nd output ----------------
// BF16IN: input is bf16 (else fp32). DUALOUT: also write raw bf16 copy of input to H2.
template <bool BF16IN, bool DUALOUT>
__global__ void bn_relu_k(const void* __restrict__ Xv, ushort_t* __restrict__ H,
                          ushort_t* __restrict__ H2,
                          const float* __restrict__ sums, const float* __restrict__ gamma,
                          const float* __restrict__ beta, float invN,
                          long total4, int mask, int F) {
  long i = (long)blockIdx.x * blockDim.x + threadIdx.x;
  if (i >= total4) return;
  long i0 = i * 4;
  int c = (int)(i0 & mask);
  float v[4];
  if constexpr (BF16IN) {
    ushort4v u = *(const ushort4v*)((const ushort_t*)Xv + i0);
#pragma unroll
    for (int j = 0; j < 4; ++j) v[j] = bf2f(u[j]);
  } else {
    float4 f4 = *(const float4*)((const float*)Xv + i0);
    v[0] = f4.x; v[1] = f4.y; v[2] = f4.z; v[3] = f4.w;
  }
  ushort4v o, o2;
#pragma unroll
  for (int j = 0; j < 4; ++j) {
    float mu = sums[c + j] * invN;
    float var = fmaf(-mu, mu, sums[F + c + j] * invN);
    float s = rsqrtf(var + BN_EPS) * gamma[c + j];
    float sh = fmaf(-mu, s, beta[c + j]);
    o[j] = f2bf(fmaxf(fmaf(v[j], s, sh), 0.f));
    if constexpr (DUALOUT) o2[j] = f2bf(v[j]);
  }
  *(ushort4v*)&H[i0] = o;
  if constexpr (DUALOUT) *(ushort4v*)&H2[i0] = o2;
}

// ---------------- all weight transposes + combined bias in one dispatch ----------------
// Tiles: b<128 W0l[256][512]; <256 W0r; <384 Wsc; <640 W1l[512][512]; <896 W1r; ==896 cbias.
__global__ __launch_bounds__(256)
void prep_weights(const float* __restrict__ W0l, const float* __restrict__ W0r,
                  const float* __restrict__ Wsc, const float* __restrict__ W1l,
                  const float* __restrict__ W1r, const float* __restrict__ bias1,
                  const float* __restrict__ bsc,
                  ushort_t* __restrict__ w0lt, ushort_t* __restrict__ w0rt,
                  ushort_t* __restrict__ wsct, ushort_t* __restrict__ w1lt,
                  ushort_t* __restrict__ w1rt, float* __restrict__ cbias) {
  int b = blockIdx.x;
  if (b == 896) {
    int i = threadIdx.x;
    cbias[i] = bias1[i] + bsc[i];
    cbias[i + 256] = bias1[i + 256] + bsc[i + 256];
    return;
  }
  const float* W;
  ushort_t* Wt;
  int K, t;
  if (b < 384) {
    K = 256; t = b & 127;
    if (b < 128)      { W = W0l; Wt = w0lt; }
    else if (b < 256) { W = W0r; Wt = w0rt; }
    else              { W = Wsc; Wt = wsct; }
  } else {
    K = 512; t = (b - 384) & 255;
    if (b < 640) { W = W1l; Wt = w1lt; }
    else         { W = W1r; Wt = w1rt; }
  }
  int Kt = K >> 5;
  int bk = (t % Kt) * 32, bn = (t / Kt) * 32;
  __shared__ ushort_t tl[32][40];
  int tx = threadIdx.x & 31, ty = threadIdx.x >> 5;  // 32 x 8
#pragma unroll
  for (int i = 0; i < 4; ++i)
    tl[ty + i * 8][tx] = f2bf(W[(size_t)(bk + ty + i * 8) * 512 + bn + tx]);
  __syncthreads();
#pragma unroll
  for (int i = 0; i < 4; ++i)
    Wt[(size_t)(bn + ty + i * 8) * K + bk + tx] = tl[tx][ty + i * 8];
}

// ---------------- XCD-grouped padded-CSR fill (single pass, no rowptr) ----------------
// Group g = blockIdx&7 handles dst in [g*1250, (g+1)*1250): atomics + writes stay in
// one XCD's L2 under round-robin block dispatch (correctness independent of mapping).
__global__ __launch_bounds__(256)
void csr_fill_g(const int* __restrict__ src, const int* __restrict__ dst,
                int* __restrict__ fill, int* __restrict__ csrc) {
  int g = blockIdx.x & 7;
  int bi = blockIdx.x >> 3;
  int bpg = gridDim.x >> 3;
  int lo = g * (N_NODES / 8);
  int hi = lo + (N_NODES / 8);
  const int nchunks = (N_EDGES + 255) / 256;
  for (int ch = bi; ch < nchunks; ch += bpg) {
    int e = ch * 256 + threadIdx.x;
    if (e < N_EDGES) {
      int d = dst[e];
      if (d >= lo && d < hi) {
        int pos = atomicAdd(&fill[d], 1);
        csrc[(size_t)d * DEG_CAP + pos] = src[e];
      }
    }
  }
}

// ---------------- gather-mean from padded CSR, bf16 in/out, fp32 accumulate ----------------
template <int F>
__global__ __launch_bounds__(64)
void gather_mean_bf(const ushort_t* __restrict__ H, const int* __restrict__ fill,
                    const int* __restrict__ csrc, ushort_t* __restrict__ agg) {
  constexpr int VEC = F / 64;  // 4 or 8
  int node = blockIdx.x;
  int c0 = threadIdx.x * VEC;
  int deg = fill[node];
  const int* cs = csrc + (size_t)node * DEG_CAP;
  float acc[VEC] = {};
  int e = 0;
  for (; e + 2 <= deg; e += 2) {
    int s0 = cs[e], s1 = cs[e + 1];
    if constexpr (VEC == 8) {
      ushort8v a = *(const ushort8v*)&H[(size_t)s0 * F + c0];
      ushort8v b = *(const ushort8v*)&H[(size_t)s1 * F + c0];
#pragma unroll
      for (int j = 0; j < 8; ++j) acc[j] += bf2f(a[j]) + bf2f(b[j]);
    } else {
      ushort4v a = *(const ushort4v*)&H[(size_t)s0 * F + c0];
      ushort4v b = *(const ushort4v*)&H[(size_t)s1 * F + c0];
#pragma unroll
      for (int j = 0; j < 4; ++j) acc[j] += bf2f(a[j]) + bf2f(b[j]);
    }
  }
  if (e < deg) {
    int s0 = cs[e];
    if constexpr (VEC == 8) {
      ushort8v a = *(const ushort8v*)&H[(size_t)s0 * F + c0];
#pragma unroll
      for (int j = 0; j < 8; ++j) acc[j] += bf2f(a[j]);
    } else {
      ushort4v a = *(const ushort4v*)&H[(size_t)s0 * F + c0];
#pragma unroll
      for (int j = 0; j < 4; ++j) acc[j] += bf2f(a[j]);
    }
  }
  float ic = 1.0f / fmaxf((float)deg, 1.0f);
  if constexpr (VEC == 8) {
    ushort8v o;
#pragma unroll
    for (int j = 0; j < 8; ++j) o[j] = f2bf(acc[j] * ic);
    *(ushort8v*)&agg[(size_t)node * F + c0] = o;
  } else {
    ushort4v o;
#pragma unroll
    for (int j = 0; j < 4; ++j) o[j] = f2bf(acc[j] * ic);
    *(ushort4v*)&agg[(size_t)node * F + c0] = o;
  }
}

// ---------------- MFMA bf16 GEMM: C = sum_s As@Bs^T + bias ----------------
// Up to 3 K-segments with compile-time lengths (0 = absent).
// A row-major [M][K] bf16; B is Wt [512][K] bf16 (N-major, k contiguous).
// 64x128 block tile, BK=64, 4 waves (2x2), each wave 32x64 via 2x4 mfma_16x16x32.
// EPI: 0 = store bf16, 1 = store f32.
#define GEMM_SEG(Aseg, Bseg, KA)                                                   \
  for (int k0 = 0; k0 < (KA); k0 += 64) {                                          \
    int gr = m0 + ar;                                                              \
    if (gr < M) {                                                                  \
      const short8* ap = (const short8*)&(Aseg)[(size_t)gr * (KA) + k0 + aq];      \
      *(short8*)&As[ar][aq] = ap[0];                                               \
      *(short8*)&As[ar][aq + 8] = ap[1];                                           \
    } else {                                                                       \
      short8 z = {};                                                               \
      *(short8*)&As[ar][aq] = z;                                                   \
      *(short8*)&As[ar][aq + 8] = z;                                               \
    }                                                                              \
    const short8* bp = (const short8*)&(Bseg)[(size_t)(n0 + br) * (KA) + k0 + bh]; \
    *(short8*)&Bs[br][bh] = bp[0];                                                 \
    *(short8*)&Bs[br][bh + 8] = bp[1];                                             \
    *(short8*)&Bs[br][bh + 16] = bp[2];                                            \
    *(short8*)&Bs[br][bh + 24] = bp[3];                                            \
    __syncthreads();                                                               \
    _Pragma("unroll")                                                              \
    for (int ks = 0; ks < 2; ++ks) {                                               \
      int kof = ks * 32 + (lane >> 4) * 8;                                         \
      int rsel = lane & 15;                                                        \
      short8 af[2], bfv[4];                                                        \
      af[0] = *(const short8*)&As[wm * 32 + rsel][kof];                            \
      af[1] = *(const short8*)&As[wm * 32 + 16 + rsel][kof];                       \
      _Pragma("unroll")                                                            \
      for (int ni = 0; ni < 4; ++ni)                                               \
        bfv[ni] = *(const short8*)&Bs[wn * 64 + ni * 16 + rsel][kof];              \
      _Pragma("unroll")                                                            \
      for (int mi = 0; mi < 2; ++mi)                                               \
        _Pragma("unroll")                                                          \
        for (int ni = 0; ni < 4; ++ni)                                             \
          acc[mi][ni] = __builtin_amdgcn_mfma_f32_16x16x32_bf16(                   \
              af[mi], bfv[ni], acc[mi][ni], 0, 0, 0);                              \
    }                                                                              \
    __syncthreads();                                                               \
  }

template <int EPI, int K0, int K1, int K2>
__global__ __launch_bounds__(256)
void gemm_mfma(const ushort_t* __restrict__ A0, const ushort_t* __restrict__ B0,
               const ushort_t* __restrict__ A1p, const ushort_t* __restrict__ B1p,
               const ushort_t* __restrict__ A2p, const ushort_t* __restrict__ B2p,
               const float* __restrict__ bias, void* __restrict__ Cv, int M) {
  __shared__ __align__(16) short As[64][72];
  __shared__ __align__(16) short Bs[128][72];

  int tid = threadIdx.x;
  int lane = tid & 63;
  int w = tid >> 6;
  int wm = w >> 1, wn = w & 1;
  int m0 = blockIdx.y * 64;
  int n0 = blockIdx.x * 128;

  int ar = tid >> 2;            // A stage: row 0..63
  int aq = (tid & 3) * 16;      // A stage: 16-elem quarter
  int br = tid >> 1;            // B stage: row 0..127
  int bh = (tid & 1) * 32;      // B stage: 32-elem half

  f32x4 acc[2][4] = {};

  GEMM_SEG(A0, B0, K0)
  if constexpr (K1 > 0) { GEMM_SEG(A1p, B1p, K1) }
  if constexpr (K2 > 0) { GEMM_SEG(A2p, B2p, K2) }

  // epilogue: D row = (lane>>4)*4 + reg, col = lane&15  [m89/m91 layout]
  int colbase = n0 + wn * 64 + (lane & 15);
  int rowq = (lane >> 4) * 4;
#pragma unroll
  for (int ni = 0; ni < 4; ++ni) {
    int col = colbase + ni * 16;
    float bv = bias[col];
#pragma unroll
    for (int mi = 0; mi < 2; ++mi) {
      int rbase = m0 + wm * 32 + mi * 16 + rowq;
#pragma unroll
      for (int r = 0; r < 4; ++r) {
        int row = rbase + r;
        if (row < M) {
          float v = acc[mi][ni][r] + bv;
          if constexpr (EPI == 0) {
            ((ushort_t*)Cv)[(size_t)row * 512 + col] = f2bf(v);
          } else {
            ((float*)Cv)[(size_t)row * 512 + col] = v;
          }
        }
      }
    }
  }
}

extern "C" void kernel_launch(void* const* d_in, const int* in_sizes, int n_in,
                              void* d_out, int out_size, void* d_ws, size_t ws_size,
                              hipStream_t stream) {
  const float* x = (const float*)d_in[0];
  const int* ei = (const int*)d_in[1];
  const int* src = ei;
  const int* dst = ei + N_EDGES;
  const float* gamma0 = (const float*)d_in[2];
  const float* beta0  = (const float*)d_in[3];
  const float* W0l    = (const float*)d_in[4];
  const float* W0r    = (const float*)d_in[5];
  const float* bias0  = (const float*)d_in[6];
  const float* gamma1 = (const float*)d_in[7];
  const float* beta1  = (const float*)d_in[8];
  const float* W1l    = (const float*)d_in[9];
  const float* W1r    = (const float*)d_in[10];
  const float* bias1  = (const float*)d_in[11];
  const float* Wsc    = (const float*)d_in[12];
  const float* bsc    = (const float*)d_in[13];
  float* out = (float*)d_out;

  char* wp = (char*)d_ws;
  ushort_t* h0b   = (ushort_t*)wp; wp += (size_t)N_NODES * FIN * 2;
  ushort_t* agg0b = (ushort_t*)wp; wp += (size_t)N_NODES * FIN * 2;
  ushort_t* h1b   = (ushort_t*)wp; wp += (size_t)N_NODES * FOUT * 2;
  ushort_t* h1rb  = (ushort_t*)wp; wp += (size_t)N_NODES * FOUT * 2;
  ushort_t* agg1b = (ushort_t*)wp; wp += (size_t)N_NODES * FOUT * 2;
  ushort_t* xb    = (ushort_t*)wp; wp += (size_t)N_NODES * FIN * 2;
  ushort_t* w0lt  = (ushort_t*)wp; wp += (size_t)FIN * FOUT * 2;   // [512][256]
  ushort_t* w0rt  = (ushort_t*)wp; wp += (size_t)FIN * FOUT * 2;
  ushort_t* wsct  = (ushort_t*)wp; wp += (size_t)FIN * FOUT * 2;
  ushort_t* w1lt  = (ushort_t*)wp; wp += (size_t)FOUT * FOUT * 2;  // [512][512]
  ushort_t* w1rt  = (ushort_t*)wp; wp += (size_t)FOUT * FOUT * 2;
  float* sums  = (float*)wp; wp += 2 * FOUT * 4;
  float* cbias = (float*)wp; wp += FOUT * 4;
  int* fill    = (int*)wp; wp += (size_t)N_NODES * 4;
  int* csrc    = (int*)wp; wp += (size_t)N_NODES * DEG_CAP * 4;

  hipMemsetAsync(sums, 0, 2 * FOUT * sizeof(float), stream);
  hipMemsetAsync(fill, 0, N_NODES * sizeof(int), stream);

  // ---- padded CSR build: one XCD-grouped pass ----
  csr_fill_g<<<2048, 256, 0, stream>>>(src, dst, fill, csrc);

  // ---- weight prep (all transposes + combined bias, one dispatch) ----
  prep_weights<<<897, 256, 0, stream>>>(W0l, W0r, Wsc, W1l, W1r, bias1, bsc,
                                        w0lt, w0rt, wsct, w1lt, w1rt, cbias);

  // ---- layer 0: BN stats, then BN+ReLU (dual out: h0b + raw xb) ----
  col_stats_f<<<N_NODES / 80, FIN, 0, stream>>>(x, N_NODES, FIN, 80, sums);
  bn_relu_k<false, true><<<(N_NODES * FIN / 4 + 255) / 256, 256, 0, stream>>>(
      x, h0b, xb, sums, gamma0, beta0, 1.0f / N_NODES,
      (long)N_NODES * FIN / 4, FIN - 1, FIN);

  // ---- layer 0: gather mean ----
  gather_mean_bf<FIN><<<N_NODES, 64, 0, stream>>>(h0b, fill, csrc, agg0b);

  // ---- layer 0 GEMM: h1 = agg0@W0l + h0@W0r + bias0 (bf16 out) ----
  gemm_mfma<0, FIN, FIN, 0><<<dim3(FOUT / 128, (N_NODES + 63) / 64), 256, 0, stream>>>(
      agg0b, w0lt, h0b, w0rt, nullptr, nullptr, bias0, h1b, N_NODES);

  // ---- layer 1: BN stats + BN+ReLU ----
  hipMemsetAsync(sums, 0, 2 * FOUT * sizeof(float), stream);
  col_stats_b<<<N_NODES / 80, FOUT, 0, stream>>>(h1b, N_NODES, FOUT, 80, sums);
  bn_relu_k<true, false><<<(N_NODES * FOUT / 4 + 255) / 256, 256, 0, stream>>>(
      h1b, h1rb, nullptr, sums, gamma1, beta1, 1.0f / N_NODES,
      (long)N_NODES * FOUT / 4, FOUT - 1, FOUT);

  // ---- layer 1: gather mean ----
  gather_mean_bf<FOUT><<<N_NODES, 64, 0, stream>>>(h1rb, fill, csrc, agg1b);

  // ---- merged GEMM: out = agg1@W1l + h1r@W1r + x@Wsc + (bias1+bsc), f32 out ----
  gemm_mfma<1, FOUT, FOUT, FIN><<<dim3(FOUT / 128, (N_NODES + 63) / 64), 256, 0, stream>>>(
      agg1b, w1lt, h1rb, w1rt, xb, wsct, cbias, out, N_NODES);
}

// Round 6
// 186.215 us; speedup vs baseline: 6.0800x; 1.0956x over previous
//
#include <hip/hip_runtime.h>
#include <hip/hip_bf16.h>
#include <cstdint>
#include <cstddef>

#define N_NODES 10000
#define N_EDGES 320000
#define FIN 256
#define FOUT 512
#define BN_EPS 1e-5f
#define DEG_CAP 128   // max degree; Binomial(320k,1e-4) max ~56 (11+ sigma margin)

typedef unsigned short ushort_t;
typedef __attribute__((ext_vector_type(8))) short short8;
typedef __attribute__((ext_vector_type(4))) float f32x4;
typedef __attribute__((ext_vector_type(4))) unsigned short ushort4v;
typedef __attribute__((ext_vector_type(8))) unsigned short ushort8v;

__device__ inline ushort_t f2bf(float f) {
  __hip_bfloat16 h = __float2bfloat16(f);  // RNE
  return *reinterpret_cast<ushort_t*>(&h);
}
__device__ inline float bf2f(ushort_t u) {
  union { unsigned int i; float f; } c;
  c.i = ((unsigned int)u) << 16;
  return c.f;
}

// ================= prologue: csr_fill (b<2048) | prep_weights (<2945) | col_stats0 =================
__global__ __launch_bounds__(256)
void prologue_k(const int* __restrict__ src, const int* __restrict__ dst,
                int* __restrict__ fill, int* __restrict__ csrc,
                const float* __restrict__ W0l, const float* __restrict__ W0r,
                const float* __restrict__ Wsc, const float* __restrict__ W1l,
                const float* __restrict__ W1r, const float* __restrict__ bias1,
                const float* __restrict__ bsc,
                ushort_t* __restrict__ w0lt, ushort_t* __restrict__ w0rt,
                ushort_t* __restrict__ wsct, ushort_t* __restrict__ w1lt,
                ushort_t* __restrict__ w1rt, float* __restrict__ cbias,
                const float* __restrict__ x, float* __restrict__ sums0) {
  __shared__ ushort_t tl[32][40];
  int b = blockIdx.x;
  if (b < 2048) {
    // ---- XCD-grouped padded-CSR fill: group g = b&7 owns dst in [g*1250,(g+1)*1250) ----
    int g = b & 7;
    int bi = b >> 3;
    const int bpg = 256;
    int lo = g * (N_NODES / 8), hi = lo + (N_NODES / 8);
    const int nchunks = (N_EDGES + 255) / 256;
    for (int ch = bi; ch < nchunks; ch += bpg) {
      int e = ch * 256 + threadIdx.x;
      if (e < N_EDGES) {
        int d = dst[e];
        if (d >= lo && d < hi) {
          int pos = atomicAdd(&fill[d], 1);
          csrc[(size_t)d * DEG_CAP + pos] = src[e];
        }
      }
    }
    return;
  }
  if (b < 2945) {
    // ---- weight transpose + bf16; tile id t within each matrix ----
    int bb = b - 2048;  // 0..896
    if (bb == 896) {
      int i = threadIdx.x;
      cbias[i] = bias1[i] + bsc[i];
      cbias[i + 256] = bias1[i + 256] + bsc[i + 256];
      return;
    }
    const float* W;
    ushort_t* Wt;
    int K, t;
    if (bb < 384) {
      K = 256; t = bb & 127;
      if (bb < 128)      { W = W0l; Wt = w0lt; }
      else if (bb < 256) { W = W0r; Wt = w0rt; }
      else               { W = Wsc; Wt = wsct; }
    } else {
      K = 512; t = (bb - 384) & 255;
      if (bb < 2048 - 2048 + 640) { W = W1l; Wt = w1lt; }  // bb < 640
      else                        { W = W1r; Wt = w1rt; }
    }
    int Kt = K >> 5;
    int bk = (t % Kt) * 32, bn = (t / Kt) * 32;
    int tx = threadIdx.x & 31, ty = threadIdx.x >> 5;  // 32 x 8
#pragma unroll
    for (int i = 0; i < 4; ++i)
      tl[ty + i * 8][tx] = f2bf(W[(size_t)(bk + ty + i * 8) * 512 + bn + tx]);
    __syncthreads();
#pragma unroll
    for (int i = 0; i < 4; ++i)
      Wt[(size_t)(bn + ty + i * 8) * K + bk + tx] = tl[tx][ty + i * 8];
    return;
  }
  // ---- BN0 column stats over x (fp32), F=256, 80 rows per block ----
  int blk = b - 2945;  // 0..124
  int c = threadIdx.x;
  int r0 = blk * 80, r1 = min(r0 + 80, N_NODES);
  float s = 0.f, q = 0.f;
  for (int r = r0; r < r1; ++r) {
    float v = x[(size_t)r * FIN + c];
    s += v;
    q = fmaf(v, v, q);
  }
  atomicAdd(&sums0[c], s);
  atomicAdd(&sums0[FIN + c], q);
}

// ================= BN+ReLU (stats finalized inline), dual out: H=bn_relu, H2=raw bf16 =================
__global__ void bn_relu0_k(const float* __restrict__ X, ushort_t* __restrict__ H,
                           ushort_t* __restrict__ H2, const float* __restrict__ sums,
                           const float* __restrict__ gamma, const float* __restrict__ beta,
                           float invN, long total4) {
  long i = (long)blockIdx.x * blockDim.x + threadIdx.x;
  if (i >= total4) return;
  long i0 = i * 4;
  int c = (int)(i0 & (FIN - 1));
  float4 f4 = *(const float4*)&X[i0];
  float v[4] = {f4.x, f4.y, f4.z, f4.w};
  ushort4v o, o2;
#pragma unroll
  for (int j = 0; j < 4; ++j) {
    float mu = sums[c + j] * invN;
    float var = fmaf(-mu, mu, sums[FIN + c + j] * invN);
    float s = rsqrtf(var + BN_EPS) * gamma[c + j];
    float sh = fmaf(-mu, s, beta[c + j]);
    o[j] = f2bf(fmaxf(fmaf(v[j], s, sh), 0.f));
    o2[j] = f2bf(v[j]);
  }
  *(ushort4v*)&H[i0] = o;
  *(ushort4v*)&H2[i0] = o2;
}

// ================= finalize BN1 scale/shift: ab[c]=scale, ab[512+c]=shift =================
__global__ void finalize_ab(const float* __restrict__ sums, const float* __restrict__ gamma,
                            const float* __restrict__ beta, float* __restrict__ ab, float invN) {
  int c = threadIdx.x;  // 512 threads
  float mu = sums[c] * invN;
  float var = fmaf(-mu, mu, sums[FOUT + c] * invN);
  float s = rsqrtf(var + BN_EPS) * gamma[c];
  ab[c] = s;
  ab[FOUT + c] = fmaf(-mu, s, beta[c]);
}

// ================= gather-mean from padded CSR; optional inline BN+ReLU =================
template <int F, bool BN>
__global__ __launch_bounds__(64)
void gather_mean_bf(const ushort_t* __restrict__ H, const int* __restrict__ fill,
                    const int* __restrict__ csrc, const float* __restrict__ ab,
                    ushort_t* __restrict__ agg) {
  constexpr int VEC = F / 64;  // 4 or 8
  int node = blockIdx.x;
  int c0 = threadIdx.x * VEC;
  int deg = fill[node];
  const int* cs = csrc + (size_t)node * DEG_CAP;
  float sc[VEC], sh[VEC];
  if constexpr (BN) {
#pragma unroll
    for (int j = 0; j < VEC; ++j) { sc[j] = ab[c0 + j]; sh[j] = ab[FOUT + c0 + j]; }
  }
  float acc[VEC] = {};
  int e = 0;
  for (; e + 2 <= deg; e += 2) {
    int s0 = cs[e], s1 = cs[e + 1];
    if constexpr (VEC == 8) {
      ushort8v a = *(const ushort8v*)&H[(size_t)s0 * F + c0];
      ushort8v b = *(const ushort8v*)&H[(size_t)s1 * F + c0];
#pragma unroll
      for (int j = 0; j < 8; ++j) {
        if constexpr (BN) {
          acc[j] += fmaxf(fmaf(bf2f(a[j]), sc[j], sh[j]), 0.f) +
                    fmaxf(fmaf(bf2f(b[j]), sc[j], sh[j]), 0.f);
        } else {
          acc[j] += bf2f(a[j]) + bf2f(b[j]);
        }
      }
    } else {
      ushort4v a = *(const ushort4v*)&H[(size_t)s0 * F + c0];
      ushort4v b = *(const ushort4v*)&H[(size_t)s1 * F + c0];
#pragma unroll
      for (int j = 0; j < 4; ++j) acc[j] += bf2f(a[j]) + bf2f(b[j]);
    }
  }
  if (e < deg) {
    int s0 = cs[e];
    if constexpr (VEC == 8) {
      ushort8v a = *(const ushort8v*)&H[(size_t)s0 * F + c0];
#pragma unroll
      for (int j = 0; j < 8; ++j) {
        if constexpr (BN) acc[j] += fmaxf(fmaf(bf2f(a[j]), sc[j], sh[j]), 0.f);
        else              acc[j] += bf2f(a[j]);
      }
    } else {
      ushort4v a = *(const ushort4v*)&H[(size_t)s0 * F + c0];
#pragma unroll
      for (int j = 0; j < 4; ++j) acc[j] += bf2f(a[j]);
    }
  }
  float ic = 1.0f / fmaxf((float)deg, 1.0f);
  if constexpr (VEC == 8) {
    ushort8v o;
#pragma unroll
    for (int j = 0; j < 8; ++j) o[j] = f2bf(acc[j] * ic);
    *(ushort8v*)&agg[(size_t)node * F + c0] = o;
  } else {
    ushort4v o;
#pragma unroll
    for (int j = 0; j < 4; ++j) o[j] = f2bf(acc[j] * ic);
    *(ushort4v*)&agg[(size_t)node * F + c0] = o;
  }
}

// ================= MFMA bf16 GEMM: C = sum_s As@Bs^T + bias =================
// 64x128 tile, BK=64, 4 waves (2x2), wave 32x64 via 2x4 mfma_16x16x32.
// BNS: segment index whose A gets inline BN+ReLU from abn (or -1).
// STATS: accumulate per-column sum/sumsq of outputs into statsOut (for next BN).
// EPI: 0 = store bf16, 1 = store f32.
#define GEMM_SEG(Aseg, Bseg, KA, DOBN)                                             \
  for (int k0 = 0; k0 < (KA); k0 += 64) {                                          \
    int gr = m0 + ar;                                                              \
    short8 a0, a1;                                                                 \
    if (gr < M) {                                                                  \
      const short8* ap = (const short8*)&(Aseg)[(size_t)gr * (KA) + k0 + aq];      \
      a0 = ap[0]; a1 = ap[1];                                                      \
      if (DOBN) {                                                                  \
        const float* abp = abn + k0 + aq;                                          \
        _Pragma("unroll")                                                          \
        for (int j = 0; j < 8; ++j) {                                              \
          a0[j] = (short)f2bf(fmaxf(fmaf(bf2f((ushort_t)a0[j]), abp[j], abp[512 + j]), 0.f));      \
          a1[j] = (short)f2bf(fmaxf(fmaf(bf2f((ushort_t)a1[j]), abp[8 + j], abp[520 + j]), 0.f));  \
        }                                                                          \
      }                                                                            \
    } else {                                                                       \
      a0 = short8{}; a1 = short8{};                                                \
    }                                                                              \
    *(short8*)&As[ar][aq] = a0;                                                    \
    *(short8*)&As[ar][aq + 8] = a1;                                                \
    const short8* bp = (const short8*)&(Bseg)[(size_t)(n0 + br) * (KA) + k0 + bh]; \
    *(short8*)&Bs[br][bh] = bp[0];                                                 \
    *(short8*)&Bs[br][bh + 8] = bp[1];                                             \
    *(short8*)&Bs[br][bh + 16] = bp[2];                                            \
    *(short8*)&Bs[br][bh + 24] = bp[3];                                            \
    __syncthreads();                                                               \
    _Pragma("unroll")                                                              \
    for (int ks = 0; ks < 2; ++ks) {                                               \
      int kof = ks * 32 + (lane >> 4) * 8;                                         \
      int rsel = lane & 15;                                                        \
      short8 af[2], bfv[4];                                                        \
      af[0] = *(const short8*)&As[wm * 32 + rsel][kof];                            \
      af[1] = *(const short8*)&As[wm * 32 + 16 + rsel][kof];                       \
      _Pragma("unroll")                                                            \
      for (int ni = 0; ni < 4; ++ni)                                               \
        bfv[ni] = *(const short8*)&Bs[wn * 64 + ni * 16 + rsel][kof];              \
      _Pragma("unroll")                                                            \
      for (int mi = 0; mi < 2; ++mi)                                               \
        _Pragma("unroll")                                                          \
        for (int ni = 0; ni < 4; ++ni)                                             \
          acc[mi][ni] = __builtin_amdgcn_mfma_f32_16x16x32_bf16(                   \
              af[mi], bfv[ni], acc[mi][ni], 0, 0, 0);                              \
    }                                                                              \
    __syncthreads();                                                               \
  }

template <int EPI, int K0, int K1, int K2, bool STATS, int BNS>
__global__ __launch_bounds__(256)
void gemm_mfma(const ushort_t* __restrict__ A0, const ushort_t* __restrict__ B0,
               const ushort_t* __restrict__ A1p, const ushort_t* __restrict__ B1p,
               const ushort_t* __restrict__ A2p, const ushort_t* __restrict__ B2p,
               const float* __restrict__ bias, void* __restrict__ Cv, int M,
               const float* __restrict__ abn, float* __restrict__ statsOut) {
  __shared__ __align__(16) short As[64][72];
  __shared__ __align__(16) short Bs[128][72];

  int tid = threadIdx.x;
  int lane = tid & 63;
  int w = tid >> 6;
  int wm = w >> 1, wn = w & 1;
  int m0 = blockIdx.y * 64;
  int n0 = blockIdx.x * 128;

  int ar = tid >> 2;         // A stage: row 0..63
  int aq = (tid & 3) * 16;   // A stage: 16-elem quarter
  int br = tid >> 1;         // B stage: row 0..127
  int bh = (tid & 1) * 32;   // B stage: 32-elem half

  f32x4 acc[2][4] = {};

  GEMM_SEG(A0, B0, K0, (BNS == 0))
  if constexpr (K1 > 0) { GEMM_SEG(A1p, B1p, K1, (BNS == 1)) }
  if constexpr (K2 > 0) { GEMM_SEG(A2p, B2p, K2, (BNS == 2)) }

  // column-stats scratch (reuse As; safe after trailing __syncthreads of K-loop)
  float* st = (float*)&As[0][0];  // [256]: st[j]=sum col j, st[128+j]=sumsq
  if constexpr (STATS) {
    if (tid < 256) st[tid] = 0.f;
    __syncthreads();
  }

  // epilogue: D row = (lane>>4)*4 + reg, col = lane&15  [m89/m91 layout]
  int colbase = n0 + wn * 64 + (lane & 15);
  int rowq = (lane >> 4) * 4;
#pragma unroll
  for (int ni = 0; ni < 4; ++ni) {
    int col = colbase + ni * 16;
    float bv = bias[col];
    float s_l = 0.f, q_l = 0.f;
#pragma unroll
    for (int mi = 0; mi < 2; ++mi) {
      int rbase = m0 + wm * 32 + mi * 16 + rowq;
#pragma unroll
      for (int r = 0; r < 4; ++r) {
        int row = rbase + r;
        if (row < M) {
          float v = acc[mi][ni][r] + bv;
          if constexpr (STATS) {
            s_l += v;
            q_l = fmaf(v, v, q_l);
          }
          if constexpr (EPI == 0) {
            ((ushort_t*)Cv)[(size_t)row * 512 + col] = f2bf(v);
          } else {
            ((float*)Cv)[(size_t)row * 512 + col] = v;
          }
        }
      }
    }
    if constexpr (STATS) {
      int cloc = wn * 64 + ni * 16 + (lane & 15);
      atomicAdd(&st[cloc], s_l);
      atomicAdd(&st[128 + cloc], q_l);
    }
  }
  if constexpr (STATS) {
    __syncthreads();
    if (tid < 256) {
      int c = tid & 127;
      atomicAdd(&statsOut[(tid >> 7) * 512 + n0 + c], st[(tid >> 7) * 128 + c]);
    }
  }
}

extern "C" void kernel_launch(void* const* d_in, const int* in_sizes, int n_in,
                              void* d_out, int out_size, void* d_ws, size_t ws_size,
                              hipStream_t stream) {
  const float* x = (const float*)d_in[0];
  const int* ei = (const int*)d_in[1];
  const int* src = ei;
  const int* dst = ei + N_EDGES;
  const float* gamma0 = (const float*)d_in[2];
  const float* beta0  = (const float*)d_in[3];
  const float* W0l    = (const float*)d_in[4];
  const float* W0r    = (const float*)d_in[5];
  const float* bias0  = (const float*)d_in[6];
  const float* gamma1 = (const float*)d_in[7];
  const float* beta1  = (const float*)d_in[8];
  const float* W1l    = (const float*)d_in[9];
  const float* W1r    = (const float*)d_in[10];
  const float* bias1  = (const float*)d_in[11];
  const float* Wsc    = (const float*)d_in[12];
  const float* bsc    = (const float*)d_in[13];
  float* out = (float*)d_out;

  char* wp = (char*)d_ws;
  ushort_t* h0b   = (ushort_t*)wp; wp += (size_t)N_NODES * FIN * 2;
  ushort_t* agg0b = (ushort_t*)wp; wp += (size_t)N_NODES * FIN * 2;
  ushort_t* h1b   = (ushort_t*)wp; wp += (size_t)N_NODES * FOUT * 2;
  ushort_t* agg1b = (ushort_t*)wp; wp += (size_t)N_NODES * FOUT * 2;
  ushort_t* xb    = (ushort_t*)wp; wp += (size_t)N_NODES * FIN * 2;
  ushort_t* w0lt  = (ushort_t*)wp; wp += (size_t)FIN * FOUT * 2;   // [512][256]
  ushort_t* w0rt  = (ushort_t*)wp; wp += (size_t)FIN * FOUT * 2;
  ushort_t* wsct  = (ushort_t*)wp; wp += (size_t)FIN * FOUT * 2;
  ushort_t* w1lt  = (ushort_t*)wp; wp += (size_t)FOUT * FOUT * 2;  // [512][512]
  ushort_t* w1rt  = (ushort_t*)wp; wp += (size_t)FOUT * FOUT * 2;
  float* cbias = (float*)wp; wp += FOUT * 4;
  float* ab1   = (float*)wp; wp += 2 * FOUT * 4;
  // contiguous zero region: sums0 (512 f) | sums1 (1024 f) | fill (10000 i)
  float* sums0 = (float*)wp; wp += 2 * FIN * 4;
  float* sums1 = (float*)wp; wp += 2 * FOUT * 4;
  int* fill    = (int*)wp; wp += (size_t)N_NODES * 4;
  int* csrc    = (int*)wp; wp += (size_t)N_NODES * DEG_CAP * 4;

  // single upfront zero of sums0+sums1+fill
  hipMemsetAsync(sums0, 0, (2 * FIN + 2 * FOUT) * 4 + N_NODES * 4, stream);

  // prologue: csr_fill | weight prep | BN0 stats (one dispatch)
  prologue_k<<<2048 + 897 + 125, 256, 0, stream>>>(
      src, dst, fill, csrc, W0l, W0r, Wsc, W1l, W1r, bias1, bsc,
      w0lt, w0rt, wsct, w1lt, w1rt, cbias, x, sums0);

  // BN0 + ReLU (dual out: h0b + raw xb)
  bn_relu0_k<<<(N_NODES * FIN / 4 + 255) / 256, 256, 0, stream>>>(
      x, h0b, xb, sums0, gamma0, beta0, 1.0f / N_NODES, (long)N_NODES * FIN / 4);

  // layer 0 gather-mean
  gather_mean_bf<FIN, false><<<N_NODES, 64, 0, stream>>>(h0b, fill, csrc, nullptr, agg0b);

  // layer 0 GEMM: h1 = agg0@W0l + h0@W0r + bias0 (bf16 out) + fused BN1 column stats
  gemm_mfma<0, FIN, FIN, 0, true, -1>
      <<<dim3(FOUT / 128, (N_NODES + 63) / 64), 256, 0, stream>>>(
      agg0b, w0lt, h0b, w0rt, nullptr, nullptr, bias0, h1b, N_NODES, nullptr, sums1);

  // BN1 scale/shift
  finalize_ab<<<1, FOUT, 0, stream>>>(sums1, gamma1, beta1, ab1, 1.0f / N_NODES);

  // layer 1 gather-mean with inline BN+ReLU (reads h1b directly)
  gather_mean_bf<FOUT, true><<<N_NODES, 64, 0, stream>>>(h1b, fill, csrc, ab1, agg1b);

  // merged GEMM: out = agg1@W1l + BN1ReLU(h1)@W1r + x@Wsc + (bias1+bsc), f32 out
  gemm_mfma<1, FOUT, FOUT, FIN, false, 1>
      <<<dim3(FOUT / 128, (N_NODES + 63) / 64), 256, 0, stream>>>(
      agg1b, w1lt, h1b, w1rt, xb, wsct, cbias, out, N_NODES, ab1, nullptr);
}